// Round 15
// baseline (628.583 us; speedup 1.0000x reference)
//
#include <hip/hip_runtime.h>

// ---------------------------------------------------------------------------
// SelfAttention (B=4,T=2048,D=1024,H=16,hd=64) fp32 in/out, bf16 MFMA compute.
// Pipeline (5 kernels): prep -> gemm_qkv11 -> flash9 (KV-split x2, 4096 waves,
// fp16 fragment-layout partials) -> reduce_o (add halves, normalize) ->
// out gemm. Exact softmax (fixed max) makes partial O/rowsum exactly additive.
//
// frag16x64 layout: matrix [R][64] stored per 16-row block:
//   addr(row,col) = (row>>4)*1024 + (col>>5)*512 + ((col>>3)&3)*128
//                 + (row&15)*8 + (col&7)
// ---------------------------------------------------------------------------

typedef __bf16 bf16_t;
typedef bf16_t bf16x8 __attribute__((ext_vector_type(8)));
typedef float  f32x4  __attribute__((ext_vector_type(4)));
typedef unsigned u32x4 __attribute__((ext_vector_type(4)));
typedef unsigned short u16x8 __attribute__((ext_vector_type(8)));
typedef unsigned short u16x4 __attribute__((ext_vector_type(4)));

#define DEV static __device__ __forceinline__

constexpr int Bc = 4, Tc = 2048, Dc = 1024, Hc = 16, HDc = 64;
constexpr int Mc = Bc * Tc;        // 8192 rows
constexpr int NQKV = 3 * Dc;       // 3072

DEV unsigned short f2bf(float f) {
  union { float f; unsigned u; } v; v.f = f;
  return (unsigned short)((v.u + 0x7fffu + ((v.u >> 16) & 1u)) >> 16);
}

DEV unsigned short f2h(float f) {
  _Float16 h = (_Float16)f;
  return __builtin_bit_cast(unsigned short, h);
}
DEV float h2f(unsigned short u) {
  _Float16 h = __builtin_bit_cast(_Float16, u);
  return (float)h;
}

DEV void gload_lds16(const void* g, const void* ldsbase) {
  unsigned m0v = __builtin_amdgcn_readfirstlane((unsigned)(unsigned long long)ldsbase);
  asm volatile("s_mov_b32 m0, %0\n\t"
               "global_load_lds_dwordx4 %1, off"
               :: "s"(m0v), "v"(g) : "memory");
}

DEV f32x4 mfma16(bf16x8 a, bf16x8 b, f32x4 c) {
  return __builtin_amdgcn_mfma_f32_16x16x32_bf16(a, b, c, 0, 0, 0);
}

DEV void pl32swap(unsigned& a, unsigned& b) {
  asm("v_permlane32_swap_b32 %0, %1" : "+v"(a), "+v"(b));
}
DEV void pl16swap(unsigned& a, unsigned& b) {
  asm("v_permlane16_swap_b32 %0, %1" : "+v"(a), "+v"(b));
}

// frag16x64 element address (row within a [R][64] matrix)
DEV int fragaddr(int row, int col) {
  return (row >> 4) * 1024 + ((col >> 5) << 9) + (((col >> 3) & 3) << 7)
       + ((row & 15) << 3) + (col & 7);
}

// ---------------------------------------------------------------------------
// prep: fused cvt_embed (blocks 0..8191) + wt_cvt (8192..9215) + bias (9216)
// ---------------------------------------------------------------------------
__global__ __launch_bounds__(256) void prep(const float* __restrict__ embed,
                                            const float* __restrict__ Wq,
                                            const float* __restrict__ Wk,
                                            const float* __restrict__ Wv,
                                            const float* __restrict__ Wo,
                                            const float* __restrict__ bq,
                                            const float* __restrict__ bk,
                                            const float* __restrict__ bv,
                                            unsigned short* __restrict__ embed_bf,
                                            unsigned short* __restrict__ WtAll,
                                            float* __restrict__ ball) {
  __shared__ unsigned short tile[64 * 80];
  const int bb = blockIdx.x;
  const int tid = threadIdx.x;

  if (bb < 8192) {                                   // ---- embed f32 -> bf16
    int i = bb * 256 + tid;
    float4 v = ((const float4*)embed)[i];
    u16x4 o = { f2bf(v.x), f2bf(v.y), f2bf(v.z), f2bf(v.w) };
    *(u16x4*)(embed_bf + (size_t)i * 4) = o;
    return;
  }
  if (bb < 8192 + 1024) {                            // ---- W -> W^T bf16
    int wb = bb - 8192;
    int bx = wb & 15, by = (wb >> 4) & 15, bz = wb >> 8;
    const float* W = bz == 0 ? Wq : bz == 1 ? Wk : bz == 2 ? Wv : Wo;
    unsigned short* dst = WtAll + (size_t)bz * 1024 * 1024;
    const int kb = by * 64, nb = bx * 64;
#pragma unroll
    for (int i = 0; i < 4; i++) {
      int ci = i * 256 + tid;
      int r = ci >> 4, c4 = ci & 15;
      float4 v = *(const float4*)(W + (size_t)(kb + r) * 1024 + nb + c4 * 4);
      u16x4 o = { f2bf(v.x), f2bf(v.y), f2bf(v.z), f2bf(v.w) };
      *(u16x4*)(tile + r * 80 + c4 * 4) = o;
    }
    __syncthreads();
#pragma unroll
    for (int i = 0; i < 2; i++) {
      int ci = i * 256 + tid;
      int n = ci >> 3, c8 = ci & 7;
      u16x8 o;
#pragma unroll
      for (int j = 0; j < 8; j++) o[j] = tile[(c8 * 8 + j) * 80 + n];
      *(u16x8*)(dst + (size_t)(nb + n) * 1024 + kb + c8 * 8) = o;
    }
    return;
  }
  // ---- bias concat (single block)
#pragma unroll
  for (int it = 0; it < 12; it++) {
    int i = it * 256 + tid;
    ball[i] = (i < 1024) ? bq[i] : (i < 2048) ? bk[i - 1024] : bv[i - 2048];
  }
}

// ---------------------------------------------------------------------------
// gemm_qkv11 (verified round-13): operand-swapped QKV projection.
// ---------------------------------------------------------------------------
__global__ __launch_bounds__(512, 2) void gemm_qkv11(
    const unsigned short* __restrict__ Wt,     // WtAll    [3072][1024]
    const unsigned short* __restrict__ Eb,     // embed_bf [8192][1024]
    const float* __restrict__ bias,            // ball[3072]
    unsigned short* __restrict__ Qf,
    unsigned short* __restrict__ Kf,
    unsigned short* __restrict__ Vf) {
  __shared__ unsigned short As_[4 * 8192];     // 64 KB (Wt rows)
  __shared__ unsigned short Bs_[4 * 8192];     // 64 KB (embed rows)

  const int tid = threadIdx.x;
  const int lane = tid & 63, wid = tid >> 6;
  const int lr = lane & 15, lg = lane >> 4;
  const int wr = wid >> 2, wc = wid & 3;

  const int lin = blockIdx.y * 12 + blockIdx.x;        // 0..383
  const int swz = (lin & 7) * 48 + (lin >> 3);
  const int m0 = (swz % 12) * 256, n0 = (swz / 12) * 256;

  size_t gA[2], gB[2];
  int ldsoff[2];
#pragma unroll
  for (int i = 0; i < 2; i++) {
    int ci = i * 512 + tid;
    int row = ci >> 2;
    int cl = (ci & 3) ^ ((row ^ (row >> 2)) & 3);
    gA[i] = (size_t)(m0 + row) * 1024 + cl * 8;
    gB[i] = (size_t)(n0 + row) * 1024 + cl * 8;
    ldsoff[i] = ci * 8;
  }

  int offA[2][4], offB[4];
#pragma unroll
  for (int mq = 0; mq < 2; mq++)
#pragma unroll
    for (int m = 0; m < 4; m++) {
      int row = wr * 128 + mq * 64 + m * 16 + lr;
      offA[mq][m] = row * 32 + ((lg ^ ((row ^ (row >> 2)) & 3)) << 3);
    }
#pragma unroll
  for (int n = 0; n < 4; n++) {
    int row = wc * 64 + n * 16 + lr;
    offB[n] = row * 32 + ((lg ^ ((row ^ (row >> 2)) & 3)) << 3);
  }

  f32x4 acc[8][4] = {};

#define QSTAGE(kt) {                                                         \
    const int sbi_ = (kt) & 3;                                               \
    _Pragma("unroll")                                                        \
    for (int i_ = 0; i_ < 2; i_++) {                                         \
      gload_lds16(Wt + gA[i_] + (size_t)(kt) * 32,                           \
                  As_ + sbi_ * 8192 + ldsoff[i_]);                           \
      gload_lds16(Eb + gB[i_] + (size_t)(kt) * 32,                           \
                  Bs_ + sbi_ * 8192 + ldsoff[i_]);                           \
    } }

#define QKTILE(kt, VM, DOST) {                                               \
    const int bi_ = (kt) & 3;                                                \
    const unsigned short* Ab = As_ + bi_ * 8192;                             \
    const unsigned short* Bb = Bs_ + bi_ * 8192;                             \
    asm volatile("s_waitcnt vmcnt(" VM ")" ::: "memory");                    \
    asm volatile("s_barrier" ::: "memory");                                  \
    bf16x8 a0 = *(const bf16x8*)(Ab + offA[0][0]);                           \
    bf16x8 a1 = *(const bf16x8*)(Ab + offA[0][1]);                           \
    bf16x8 a2 = *(const bf16x8*)(Ab + offA[0][2]);                           \
    bf16x8 a3 = *(const bf16x8*)(Ab + offA[0][3]);                           \
    bf16x8 b0 = *(const bf16x8*)(Bb + offB[0]);                              \
    bf16x8 b1 = *(const bf16x8*)(Bb + offB[1]);                              \
    bf16x8 b2 = *(const bf16x8*)(Bb + offB[2]);                              \
    bf16x8 b3 = *(const bf16x8*)(Bb + offB[3]);                              \
    if (DOST) QSTAGE((kt) + 3);                                              \
    __builtin_amdgcn_s_setprio(1);                                           \
    acc[0][0]=mfma16(a0,b0,acc[0][0]); acc[0][1]=mfma16(a0,b1,acc[0][1]);    \
    acc[0][2]=mfma16(a0,b2,acc[0][2]); acc[0][3]=mfma16(a0,b3,acc[0][3]);    \
    acc[1][0]=mfma16(a1,b0,acc[1][0]); acc[1][1]=mfma16(a1,b1,acc[1][1]);    \
    acc[1][2]=mfma16(a1,b2,acc[1][2]); acc[1][3]=mfma16(a1,b3,acc[1][3]);    \
    acc[2][0]=mfma16(a2,b0,acc[2][0]); acc[2][1]=mfma16(a2,b1,acc[2][1]);    \
    acc[2][2]=mfma16(a2,b2,acc[2][2]); acc[2][3]=mfma16(a2,b3,acc[2][3]);    \
    acc[3][0]=mfma16(a3,b0,acc[3][0]); acc[3][1]=mfma16(a3,b1,acc[3][1]);    \
    acc[3][2]=mfma16(a3,b2,acc[3][2]); acc[3][3]=mfma16(a3,b3,acc[3][3]);    \
    __builtin_amdgcn_s_setprio(0);                                           \
    a0 = *(const bf16x8*)(Ab + offA[1][0]);                                  \
    a1 = *(const bf16x8*)(Ab + offA[1][1]);                                  \
    a2 = *(const bf16x8*)(Ab + offA[1][2]);                                  \
    a3 = *(const bf16x8*)(Ab + offA[1][3]);                                  \
    __builtin_amdgcn_s_setprio(1);                                           \
    acc[4][0]=mfma16(a0,b0,acc[4][0]); acc[4][1]=mfma16(a0,b1,acc[4][1]);    \
    acc[4][2]=mfma16(a0,b2,acc[4][2]); acc[4][3]=mfma16(a0,b3,acc[4][3]);    \
    acc[5][0]=mfma16(a1,b0,acc[5][0]); acc[5][1]=mfma16(a1,b1,acc[5][1]);    \
    acc[5][2]=mfma16(a1,b2,acc[5][2]); acc[5][3]=mfma16(a1,b3,acc[5][3]);    \
    acc[6][0]=mfma16(a2,b0,acc[6][0]); acc[6][1]=mfma16(a2,b1,acc[6][1]);    \
    acc[6][2]=mfma16(a2,b2,acc[6][2]); acc[6][3]=mfma16(a2,b3,acc[6][3]);    \
    acc[7][0]=mfma16(a3,b0,acc[7][0]); acc[7][1]=mfma16(a3,b1,acc[7][1]);    \
    acc[7][2]=mfma16(a3,b2,acc[7][2]); acc[7][3]=mfma16(a3,b3,acc[7][3]);    \
    __builtin_amdgcn_s_setprio(0); }

  // prologue: 3 K-tiles in flight
  QSTAGE(0); QSTAGE(1); QSTAGE(2);

#pragma unroll 1
  for (int kt = 0; kt < 29; ++kt) {
    QKTILE(kt, "8", 1);
  }
  QKTILE(29, "8", 0);
  QKTILE(30, "4", 0);
  QKTILE(31, "0", 0);
#undef QSTAGE
#undef QKTILE

  // ------------------------- epilogue ---------------------------------
  const int ft = m0 >> 8;                            // feature-tile 0..11
  if (ft < 8) {
    // Q/K: flash-verified relayout -> coalesced frag16x64 stores.
#pragma unroll
    for (int g = 0; g < 2; g++) {                    // 64-feature group
      const int fb = m0 + wr * 128 + g * 64;
      const bool isQ = (fb < Dc);
      unsigned short* const dstm = isQ ? Qf : Kf;
      const int head = (isQ ? fb : fb - Dc) >> 6;
      float4 b4[4];
#pragma unroll
      for (int mq = 0; mq < 4; mq++)
        b4[mq] = *(const float4*)(bias + fb + mq * 16 + lg * 4);
#pragma unroll
      for (int n = 0; n < 4; n++) {
        unsigned w8[4][2];
#pragma unroll
        for (int mq = 0; mq < 4; mq++) {
          float e0 = acc[g * 4 + mq][n][0] + b4[mq].x;
          float e1 = acc[g * 4 + mq][n][1] + b4[mq].y;
          float e2 = acc[g * 4 + mq][n][2] + b4[mq].z;
          float e3 = acc[g * 4 + mq][n][3] + b4[mq].w;
          if (isQ) {
            e0 *= 0.18033688f; e1 *= 0.18033688f;    // (1/8)*log2(e)
            e2 *= 0.18033688f; e3 *= 0.18033688f;
          }
          asm("v_cvt_pk_bf16_f32 %0, %1, %2" : "=v"(w8[mq][0]) : "v"(e0), "v"(e1));
          asm("v_cvt_pk_bf16_f32 %0, %1, %2" : "=v"(w8[mq][1]) : "v"(e2), "v"(e3));
        }
        const int t = n0 + wc * 64 + n * 16;         // token base (lr within)
        const int bb = t >> 11, tl = t & 2047;
        unsigned short* dst = dstm + (size_t)(bb * 16 + head) * 131072
                            + (tl >> 4) * 1024;
#pragma unroll
        for (int half = 0; half < 2; half++) {
          unsigned a0 = w8[2 * half][0], c0 = w8[2 * half + 1][0];
          unsigned a1 = w8[2 * half][1], c1 = w8[2 * half + 1][1];
          pl32swap(a0, c0);
          pl32swap(a1, c1);
          pl16swap(a0, c0);
          pl16swap(a1, c1);
          u32x4 w = { a0, a1, c0, c1 };
          *(u32x4*)(dst + half * 512 + lane * 8) = w;
        }
      }
    }
  } else {
    // V: scatter into V^T frag16x64 (verified path)
#pragma unroll
    for (int m = 0; m < 8; m++)
#pragma unroll
      for (int n = 0; n < 4; n++)
#pragma unroll
        for (int r = 0; r < 4; r++) {
          int f = m0 + wr * 128 + m * 16 + lg * 4 + r;
          int t = n0 + wc * 64 + n * 16 + lr;
          float v = acc[m][n][r] + bias[f];
          int c = f - 2 * Dc, head = c >> 6, d = c & 63;
          int bb = t >> 11, tl = t & 2047;
          Vf[(size_t)(bb * 16 + head) * 131072 + (tl >> 6) * 4096
             + fragaddr(d, tl & 63)] = f2bf(v);
        }
  }
}

// ---------------------------------------------------------------------------
// gemm_bt (verified 128x128 structure) -- output projection, fp32 out.
// ---------------------------------------------------------------------------
__global__ __launch_bounds__(256) void gemm_bt(const unsigned short* __restrict__ A,
                                               const unsigned short* __restrict__ Bt,
                                               const float* __restrict__ bias,
                                               float* __restrict__ Cout,
                                               int N, int K) {
  __shared__ unsigned short As[128 * 64];
  __shared__ unsigned short Bs[128 * 64];
  const int tid = threadIdx.x;
  const int lane = tid & 63, wid = tid >> 6;
  const int lr = lane & 15, lg = lane >> 4;
  const int wrow = wid >> 1, wcol = wid & 1;
  const int m0 = blockIdx.y * 128, n0 = blockIdx.x * 128;

  f32x4 acc[4][4] = {};

  for (int k0 = 0; k0 < K; k0 += 64) {
#pragma unroll
    for (int i = 0; i < 4; i++) {
      int ci = i * 256 + tid;
      int row = ci >> 3, ph = ci & 7;
      int cl = ph ^ (row & 7);
      gload_lds16(A + (size_t)(m0 + row) * K + k0 + cl * 8, As + (size_t)(i * 256 + wid * 64) * 8);
      gload_lds16(Bt + (size_t)(n0 + row) * K + k0 + cl * 8, Bs + (size_t)(i * 256 + wid * 64) * 8);
    }
    asm volatile("s_waitcnt vmcnt(0)" ::: "memory");
    __syncthreads();
#pragma unroll
    for (int kk = 0; kk < 2; kk++) {
      bf16x8 av[4], bv[4];
#pragma unroll
      for (int m = 0; m < 4; m++) {
        int row = wrow * 64 + m * 16 + lr;
        int ph = (kk * 4 + lg) ^ (row & 7);
        av[m] = *(const bf16x8*)(As + row * 64 + ph * 8);
      }
#pragma unroll
      for (int n = 0; n < 4; n++) {
        int row = wcol * 64 + n * 16 + lr;
        int ph = (kk * 4 + lg) ^ (row & 7);
        bv[n] = *(const bf16x8*)(Bs + row * 64 + ph * 8);
      }
#pragma unroll
      for (int m = 0; m < 4; m++)
#pragma unroll
        for (int n = 0; n < 4; n++)
          acc[m][n] = mfma16(av[m], bv[n], acc[m][n]);
    }
    __syncthreads();
  }

#pragma unroll
  for (int m = 0; m < 4; m++)
#pragma unroll
    for (int n = 0; n < 4; n++)
#pragma unroll
      for (int r = 0; r < 4; r++) {
        int row = m0 + wrow * 64 + m * 16 + lg * 4 + r;
        int col = n0 + wcol * 64 + n * 16 + lr;
        Cout[(size_t)row * N + col] = acc[m][n][r] + bias[col];
      }
}

// ---------------------------------------------------------------------------
// flash9: KV-split flash attention. Loop body identical to verified flash7/8;
// each wave processes HALF the KV range (exact softmax => partials add).
// Grid (8, 64) = 512 blocks x 8 waves = 4096 waves = 4 waves/SIMD.
// Partial O stored fp16 in per-lane fragment layout (coalesced 16B stores);
// partial rowsum fp16. reduce_o adds halves & normalizes.
// ---------------------------------------------------------------------------
__global__ __launch_bounds__(512, 4) void flash9(const unsigned short* __restrict__ Qf,
                                                 const unsigned short* __restrict__ Kf,
                                                 const unsigned short* __restrict__ Vf,
                                                 const int* __restrict__ mask,
                                                 unsigned short* __restrict__ Opart,
                                                 unsigned short* __restrict__ Lpart) {
  const int tid = threadIdx.x;
  const int lane = tid & 63, wid = tid >> 6;   // wid 0..7
  const int lr = lane & 15, lg = lane >> 4;

  const int lin = blockIdx.y * 8 + blockIdx.x;      // 0..511
  const int swz = (lin & 7) * 64 + (lin >> 3);      // xcd = lin&7 -> 8 heads/XCD
  const int kvh = swz & 1, qb = (swz >> 1) & 3, bh = swz >> 3;
  const int b = bh >> 4, h = bh & 15;
  const int wq = qb * 512 + wid * 64;               // wave's q base

  const unsigned short* Qb = Qf + (size_t)bh * 131072;
  const unsigned short* Kb = Kf + (size_t)bh * 131072;
  const unsigned short* Vb = Vf + (size_t)bh * 131072;

  bf16x8 qf[4][2];
#pragma unroll
  for (int qn = 0; qn < 4; qn++)
#pragma unroll
    for (int kk = 0; kk < 2; kk++)
      qf[qn][kk] = *(const bf16x8*)(Qb + ((wq >> 4) + qn) * 1024 + kk * 512 + lane * 8);

  f32x4 o[4][4] = {};
  f32x4 lacc[4] = {};

  bf16x8 ones;
#pragma unroll
  for (int j = 0; j < 8; j++) ones[j] = (bf16_t)1.0f;

  // whole-mask all-ones check (8 coalesced int4 loads), hoisted
  bool allone = true;
#pragma unroll
  for (int j = 0; j < 8; j++) {
    int4 mv = ((const int4*)mask)[j * 64 + lane];
    allone = allone && (mv.x != 0) && (mv.y != 0) && (mv.z != 0) && (mv.w != 0);
  }
  const bool nomask = (__ballot(allone) == ~0ull);

  const int t0 = kvh * 16, t1 = t0 + 16;
#pragma unroll 2
  for (int tile = t0; tile < t1; tile++) {
    bf16x8 kf[4][2];
#pragma unroll
    for (int n = 0; n < 4; n++)
#pragma unroll
      for (int kk = 0; kk < 2; kk++)
        kf[n][kk] = *(const bf16x8*)(Kb + (tile * 4 + n) * 1024 + kk * 512 + lane * 8);
    bf16x8 vf[4][2];
#pragma unroll
    for (int dn = 0; dn < 4; dn++)
#pragma unroll
      for (int kk = 0; kk < 2; kk++)
        vf[dn][kk] = *(const bf16x8*)(Vb + tile * 4096 + dn * 1024 + kk * 512 + lane * 8);

    unsigned long long mb = ~0ull;
    if (!nomask) mb = __ballot(mask[tile * 64 + lane] != 0);

    unsigned pk[4][4][2];
#pragma unroll
    for (int kvn = 0; kvn < 4; kvn++) {
      f32x4 st[4] = {};
#pragma unroll
      for (int qn = 0; qn < 4; qn++) {
        st[qn] = mfma16(kf[kvn][0], qf[qn][0], st[qn]);
        st[qn] = mfma16(kf[kvn][1], qf[qn][1], st[qn]);
      }
      if (mb != ~0ull) {
#pragma unroll
        for (int r = 0; r < 4; r++)
          if (!((mb >> (kvn * 16 + lg * 4 + r)) & 1ull)) {
#pragma unroll
            for (int qn = 0; qn < 4; qn++) st[qn][r] = -1e30f;
          }
      }
#pragma unroll
      for (int qn = 0; qn < 4; qn++) {
        float e[4];
#pragma unroll
        for (int r = 0; r < 4; r++)
          asm("v_exp_f32 %0, %1" : "=v"(e[r]) : "v"(st[qn][r]));
        asm("v_cvt_pk_bf16_f32 %0, %1, %2" : "=v"(pk[qn][kvn][0]) : "v"(e[0]), "v"(e[1]));
        asm("v_cvt_pk_bf16_f32 %0, %1, %2" : "=v"(pk[qn][kvn][1]) : "v"(e[2]), "v"(e[3]));
      }
    }

    bf16x8 pa[4][2];
#pragma unroll
    for (int qn = 0; qn < 4; qn++)
#pragma unroll
      for (int m = 0; m < 2; m++) {
        unsigned a0 = pk[qn][2 * m][0], b0 = pk[qn][2 * m + 1][0];
        unsigned a1 = pk[qn][2 * m][1], b1 = pk[qn][2 * m + 1][1];
        pl32swap(a0, b0);
        pl32swap(a1, b1);
        pl16swap(a0, b0);
        pl16swap(a1, b1);
        u32x4 w = { a0, a1, b0, b1 };
        pa[qn][m] = __builtin_bit_cast(bf16x8, w);
      }

    __builtin_amdgcn_s_setprio(1);
#pragma unroll
    for (int qn = 0; qn < 4; qn++) {
#pragma unroll
      for (int dn = 0; dn < 4; dn++) {
        o[qn][dn] = mfma16(pa[qn][0], vf[dn][0], o[qn][dn]);
        o[qn][dn] = mfma16(pa[qn][1], vf[dn][1], o[qn][dn]);
      }
      lacc[qn] = mfma16(pa[qn][0], ones, lacc[qn]);
      lacc[qn] = mfma16(pa[qn][1], ones, lacc[qn]);
    }
    __builtin_amdgcn_s_setprio(0);
  }

  // epilogue: fp16 partial O in per-lane fragment layout (coalesced) + lacc.
  // f16 index within lane: j = qn*16 + dn*4 + r.
  const int c = (bh * 4 + qb) * 8 + wid;            // 0..2047
  unsigned short* ob = Opart + (size_t)c * 8192 + kvh * 4096 + lane * 64;
#pragma unroll
  for (int qn = 0; qn < 4; qn++) {
    unsigned p[8];
#pragma unroll
    for (int dn = 0; dn < 4; dn++) {
      asm("v_cvt_pkrtz_f16_f32 %0, %1, %2" : "=v"(p[dn * 2]) : "v"(o[qn][dn][0]), "v"(o[qn][dn][1]));
      asm("v_cvt_pkrtz_f16_f32 %0, %1, %2" : "=v"(p[dn * 2 + 1]) : "v"(o[qn][dn][2]), "v"(o[qn][dn][3]));
    }
    u32x4 wlo = { p[0], p[1], p[2], p[3] };
    u32x4 whi = { p[4], p[5], p[6], p[7] };
    *(u32x4*)(ob + qn * 16) = wlo;
    *(u32x4*)(ob + qn * 16 + 8) = whi;
  }
  if (lr == 0) {
#pragma unroll
    for (int qn = 0; qn < 4; qn++)
#pragma unroll
      for (int r = 0; r < 4; r++) {
        int row = qn * 16 + lg * 4 + r;
        Lpart[(size_t)c * 128 + kvh * 64 + row] = f2h(lacc[qn][r]);
      }
  }
}

// ---------------------------------------------------------------------------
// reduce_o: merged = (o0 + o1) / (l0 + l1), decoded from fragment layout.
// 512 blocks x 256 threads; thread = (c, lane).
// ---------------------------------------------------------------------------
__global__ __launch_bounds__(256) void reduce_o(const unsigned short* __restrict__ Opart,
                                                const unsigned short* __restrict__ Lpart,
                                                unsigned short* __restrict__ merged) {
  const int t = blockIdx.x * 256 + threadIdx.x;     // 0..131071
  const int c = t >> 6, lane = t & 63;
  const int bh = c >> 5, qb = (c >> 3) & 3, wid = c & 7;
  const int b = bh >> 4, h = bh & 15;
  const int lg = lane >> 4, lr = lane & 15;

  const unsigned short* o0 = Opart + (size_t)c * 8192 + lane * 64;
  const unsigned short* o1 = o0 + 4096;

  float linv[16];
#pragma unroll
  for (int qn = 0; qn < 4; qn++)
#pragma unroll
    for (int r = 0; r < 4; r++) {
      int row = qn * 16 + lg * 4 + r;
      float l0 = h2f(Lpart[(size_t)c * 128 + row]);
      float l1 = h2f(Lpart[(size_t)c * 128 + 64 + row]);
      linv[qn * 4 + r] = 1.0f / (l0 + l1);
    }

#pragma unroll
  for (int qn = 0; qn < 4; qn++) {
    u16x8 a0 = *(const u16x8*)(o0 + qn * 16);
    u16x8 a1 = *(const u16x8*)(o0 + qn * 16 + 8);
    u16x8 c0 = *(const u16x8*)(o1 + qn * 16);
    u16x8 c1 = *(const u16x8*)(o1 + qn * 16 + 8);
#pragma unroll
    for (int dn = 0; dn < 4; dn++)
#pragma unroll
      for (int r = 0; r < 4; r++) {
        int j = dn * 4 + r;
        unsigned short h0 = (j < 8) ? a0[j] : a1[j - 8];
        unsigned short h1 = (j < 8) ? c0[j] : c1[j - 8];
        float s = h2f(h0) + h2f(h1);
        int q = qb * 512 + wid * 64 + qn * 16 + lg * 4 + r;
        int d = dn * 16 + lr;
        merged[((size_t)(b * 2048 + q)) * 1024 + h * 64 + d] = f2bf(s * linv[qn * 4 + r]);
      }
  }
}

// ---------------------------------------------------------------------------
extern "C" void kernel_launch(void* const* d_in, const int* in_sizes, int n_in,
                              void* d_out, int out_size, void* d_ws, size_t ws_size,
                              hipStream_t stream) {
  const float* embed = (const float*)d_in[0];
  const int*   mask  = (const int*)d_in[1];
  const float* Wq = (const float*)d_in[2];
  const float* bq = (const float*)d_in[3];
  const float* Wk = (const float*)d_in[4];
  const float* bk = (const float*)d_in[5];
  const float* Wv = (const float*)d_in[6];
  const float* bv = (const float*)d_in[7];
  const float* Wo = (const float*)d_in[8];
  const float* bo = (const float*)d_in[9];
  float* out = (float*)d_out;

  // Layout: persistent buffers first; embed_bf/ball are dead after gemm_qkv11
  // and get overlaid by the fp16 partial-O buffer of flash9.
  char* ws = (char*)d_ws;
  unsigned short* WtAll  = (unsigned short*)ws; ws += (size_t)4 * Dc * Dc * 2;   //  8.4 MB
  unsigned short* Qf     = (unsigned short*)ws; ws += (size_t)Mc * Dc * 2;       // 16.8 MB
  unsigned short* Kf     = (unsigned short*)ws; ws += (size_t)Mc * Dc * 2;       // 16.8 MB
  unsigned short* Vf     = (unsigned short*)ws; ws += (size_t)Mc * Dc * 2;       // 16.8 MB
  unsigned short* merged = (unsigned short*)ws; ws += (size_t)Mc * Dc * 2;       // 16.8 MB
  unsigned short* embed_bf = (unsigned short*)ws;                                 // overlay base
  unsigned short* Opart    = embed_bf;          ws += (size_t)Mc * Dc * 2;       // 16.8 MB
  float*          ball     = (float*)ws;        ws += 16384;                     // 16 KB
  // Opart continues past embed_bf+ball: total 2048 * 8192 * 2 B = 33.55 MB
  ws += (size_t)2048 * 8192 * 2 - ((size_t)Mc * Dc * 2 + 16384);
  unsigned short* Lpart  = (unsigned short*)ws; ws += (size_t)2048 * 128 * 2;    //  0.5 MB

  prep<<<8192 + 1024 + 1, 256, 0, stream>>>(embed, Wq, Wk, Wv, Wo, bq, bk, bv,
                                            embed_bf, WtAll, ball);
  gemm_qkv11<<<dim3(12, 32), 512, 0, stream>>>(WtAll, embed_bf, ball, Qf, Kf, Vf);
  flash9<<<dim3(8, 64), 512, 0, stream>>>(Qf, Kf, Vf, mask, Opart, Lpart);
  reduce_o<<<512, 256, 0, stream>>>(Opart, Lpart, merged);
  gemm_bt<<<dim3(8, 64), 256, 0, stream>>>(merged, WtAll + (size_t)3 * Dc * Dc, bo, out, Dc, Dc);
}

// Round 16
// 204.671 us; speedup vs baseline: 3.0712x; 3.0712x over previous
//
#include <hip/hip_runtime.h>

// ---------------------------------------------------------------------------
// SelfAttention (B=4,T=2048,D=1024,H=16,hd=64) fp32 in/out, bf16 MFMA compute.
// Pipeline (5 kernels): prep -> gemm_qkv11 -> flash10 (KV-split x2, 4096
// waves, fp16 fragment-layout partials; plain launch_bounds so the allocator
// keeps the ~124-VGPR live set in registers) -> reduce_o -> out gemm.
// Exact softmax (fixed max) makes partial O/rowsum exactly additive.
//
// frag16x64 layout: matrix [R][64] stored per 16-row block:
//   addr(row,col) = (row>>4)*1024 + (col>>5)*512 + ((col>>3)&3)*128
//                 + (row&15)*8 + (col&7)
// ---------------------------------------------------------------------------

typedef __bf16 bf16_t;
typedef bf16_t bf16x8 __attribute__((ext_vector_type(8)));
typedef float  f32x4  __attribute__((ext_vector_type(4)));
typedef unsigned u32x4 __attribute__((ext_vector_type(4)));
typedef unsigned short u16x8 __attribute__((ext_vector_type(8)));
typedef unsigned short u16x4 __attribute__((ext_vector_type(4)));

#define DEV static __device__ __forceinline__

constexpr int Bc = 4, Tc = 2048, Dc = 1024, Hc = 16, HDc = 64;
constexpr int Mc = Bc * Tc;        // 8192 rows
constexpr int NQKV = 3 * Dc;       // 3072

DEV unsigned short f2bf(float f) {
  union { float f; unsigned u; } v; v.f = f;
  return (unsigned short)((v.u + 0x7fffu + ((v.u >> 16) & 1u)) >> 16);
}

DEV unsigned short f2h(float f) {
  _Float16 h = (_Float16)f;
  return __builtin_bit_cast(unsigned short, h);
}
DEV float h2f(unsigned short u) {
  _Float16 h = __builtin_bit_cast(_Float16, u);
  return (float)h;
}

DEV void gload_lds16(const void* g, const void* ldsbase) {
  unsigned m0v = __builtin_amdgcn_readfirstlane((unsigned)(unsigned long long)ldsbase);
  asm volatile("s_mov_b32 m0, %0\n\t"
               "global_load_lds_dwordx4 %1, off"
               :: "s"(m0v), "v"(g) : "memory");
}

DEV f32x4 mfma16(bf16x8 a, bf16x8 b, f32x4 c) {
  return __builtin_amdgcn_mfma_f32_16x16x32_bf16(a, b, c, 0, 0, 0);
}

DEV void pl32swap(unsigned& a, unsigned& b) {
  asm("v_permlane32_swap_b32 %0, %1" : "+v"(a), "+v"(b));
}
DEV void pl16swap(unsigned& a, unsigned& b) {
  asm("v_permlane16_swap_b32 %0, %1" : "+v"(a), "+v"(b));
}

// frag16x64 element address (row within a [R][64] matrix)
DEV int fragaddr(int row, int col) {
  return (row >> 4) * 1024 + ((col >> 5) << 9) + (((col >> 3) & 3) << 7)
       + ((row & 15) << 3) + (col & 7);
}

// ---------------------------------------------------------------------------
// prep: fused cvt_embed (blocks 0..8191) + wt_cvt (8192..9215) + bias (9216)
// ---------------------------------------------------------------------------
__global__ __launch_bounds__(256) void prep(const float* __restrict__ embed,
                                            const float* __restrict__ Wq,
                                            const float* __restrict__ Wk,
                                            const float* __restrict__ Wv,
                                            const float* __restrict__ Wo,
                                            const float* __restrict__ bq,
                                            const float* __restrict__ bk,
                                            const float* __restrict__ bv,
                                            unsigned short* __restrict__ embed_bf,
                                            unsigned short* __restrict__ WtAll,
                                            float* __restrict__ ball) {
  __shared__ unsigned short tile[64 * 80];
  const int bb = blockIdx.x;
  const int tid = threadIdx.x;

  if (bb < 8192) {                                   // ---- embed f32 -> bf16
    int i = bb * 256 + tid;
    float4 v = ((const float4*)embed)[i];
    u16x4 o = { f2bf(v.x), f2bf(v.y), f2bf(v.z), f2bf(v.w) };
    *(u16x4*)(embed_bf + (size_t)i * 4) = o;
    return;
  }
  if (bb < 8192 + 1024) {                            // ---- W -> W^T bf16
    int wb = bb - 8192;
    int bx = wb & 15, by = (wb >> 4) & 15, bz = wb >> 8;
    const float* W = bz == 0 ? Wq : bz == 1 ? Wk : bz == 2 ? Wv : Wo;
    unsigned short* dst = WtAll + (size_t)bz * 1024 * 1024;
    const int kb = by * 64, nb = bx * 64;
#pragma unroll
    for (int i = 0; i < 4; i++) {
      int ci = i * 256 + tid;
      int r = ci >> 4, c4 = ci & 15;
      float4 v = *(const float4*)(W + (size_t)(kb + r) * 1024 + nb + c4 * 4);
      u16x4 o = { f2bf(v.x), f2bf(v.y), f2bf(v.z), f2bf(v.w) };
      *(u16x4*)(tile + r * 80 + c4 * 4) = o;
    }
    __syncthreads();
#pragma unroll
    for (int i = 0; i < 2; i++) {
      int ci = i * 256 + tid;
      int n = ci >> 3, c8 = ci & 7;
      u16x8 o;
#pragma unroll
      for (int j = 0; j < 8; j++) o[j] = tile[(c8 * 8 + j) * 80 + n];
      *(u16x8*)(dst + (size_t)(nb + n) * 1024 + kb + c8 * 8) = o;
    }
    return;
  }
  // ---- bias concat (single block)
#pragma unroll
  for (int it = 0; it < 12; it++) {
    int i = it * 256 + tid;
    ball[i] = (i < 1024) ? bq[i] : (i < 2048) ? bk[i - 1024] : bv[i - 2048];
  }
}

// ---------------------------------------------------------------------------
// gemm_qkv11 (verified round-13): operand-swapped QKV projection.
// ---------------------------------------------------------------------------
__global__ __launch_bounds__(512, 2) void gemm_qkv11(
    const unsigned short* __restrict__ Wt,     // WtAll    [3072][1024]
    const unsigned short* __restrict__ Eb,     // embed_bf [8192][1024]
    const float* __restrict__ bias,            // ball[3072]
    unsigned short* __restrict__ Qf,
    unsigned short* __restrict__ Kf,
    unsigned short* __restrict__ Vf) {
  __shared__ unsigned short As_[4 * 8192];     // 64 KB (Wt rows)
  __shared__ unsigned short Bs_[4 * 8192];     // 64 KB (embed rows)

  const int tid = threadIdx.x;
  const int lane = tid & 63, wid = tid >> 6;
  const int lr = lane & 15, lg = lane >> 4;
  const int wr = wid >> 2, wc = wid & 3;

  const int lin = blockIdx.y * 12 + blockIdx.x;        // 0..383
  const int swz = (lin & 7) * 48 + (lin >> 3);
  const int m0 = (swz % 12) * 256, n0 = (swz / 12) * 256;

  size_t gA[2], gB[2];
  int ldsoff[2];
#pragma unroll
  for (int i = 0; i < 2; i++) {
    int ci = i * 512 + tid;
    int row = ci >> 2;
    int cl = (ci & 3) ^ ((row ^ (row >> 2)) & 3);
    gA[i] = (size_t)(m0 + row) * 1024 + cl * 8;
    gB[i] = (size_t)(n0 + row) * 1024 + cl * 8;
    ldsoff[i] = ci * 8;
  }

  int offA[2][4], offB[4];
#pragma unroll
  for (int mq = 0; mq < 2; mq++)
#pragma unroll
    for (int m = 0; m < 4; m++) {
      int row = wr * 128 + mq * 64 + m * 16 + lr;
      offA[mq][m] = row * 32 + ((lg ^ ((row ^ (row >> 2)) & 3)) << 3);
    }
#pragma unroll
  for (int n = 0; n < 4; n++) {
    int row = wc * 64 + n * 16 + lr;
    offB[n] = row * 32 + ((lg ^ ((row ^ (row >> 2)) & 3)) << 3);
  }

  f32x4 acc[8][4] = {};

#define QSTAGE(kt) {                                                         \
    const int sbi_ = (kt) & 3;                                               \
    _Pragma("unroll")                                                        \
    for (int i_ = 0; i_ < 2; i_++) {                                         \
      gload_lds16(Wt + gA[i_] + (size_t)(kt) * 32,                           \
                  As_ + sbi_ * 8192 + ldsoff[i_]);                           \
      gload_lds16(Eb + gB[i_] + (size_t)(kt) * 32,                           \
                  Bs_ + sbi_ * 8192 + ldsoff[i_]);                           \
    } }

#define QKTILE(kt, VM, DOST) {                                               \
    const int bi_ = (kt) & 3;                                                \
    const unsigned short* Ab = As_ + bi_ * 8192;                             \
    const unsigned short* Bb = Bs_ + bi_ * 8192;                             \
    asm volatile("s_waitcnt vmcnt(" VM ")" ::: "memory");                    \
    asm volatile("s_barrier" ::: "memory");                                  \
    bf16x8 a0 = *(const bf16x8*)(Ab + offA[0][0]);                           \
    bf16x8 a1 = *(const bf16x8*)(Ab + offA[0][1]);                           \
    bf16x8 a2 = *(const bf16x8*)(Ab + offA[0][2]);                           \
    bf16x8 a3 = *(const bf16x8*)(Ab + offA[0][3]);                           \
    bf16x8 b0 = *(const bf16x8*)(Bb + offB[0]);                              \
    bf16x8 b1 = *(const bf16x8*)(Bb + offB[1]);                              \
    bf16x8 b2 = *(const bf16x8*)(Bb + offB[2]);                              \
    bf16x8 b3 = *(const bf16x8*)(Bb + offB[3]);                              \
    if (DOST) QSTAGE((kt) + 3);                                              \
    __builtin_amdgcn_s_setprio(1);                                           \
    acc[0][0]=mfma16(a0,b0,acc[0][0]); acc[0][1]=mfma16(a0,b1,acc[0][1]);    \
    acc[0][2]=mfma16(a0,b2,acc[0][2]); acc[0][3]=mfma16(a0,b3,acc[0][3]);    \
    acc[1][0]=mfma16(a1,b0,acc[1][0]); acc[1][1]=mfma16(a1,b1,acc[1][1]);    \
    acc[1][2]=mfma16(a1,b2,acc[1][2]); acc[1][3]=mfma16(a1,b3,acc[1][3]);    \
    acc[2][0]=mfma16(a2,b0,acc[2][0]); acc[2][1]=mfma16(a2,b1,acc[2][1]);    \
    acc[2][2]=mfma16(a2,b2,acc[2][2]); acc[2][3]=mfma16(a2,b3,acc[2][3]);    \
    acc[3][0]=mfma16(a3,b0,acc[3][0]); acc[3][1]=mfma16(a3,b1,acc[3][1]);    \
    acc[3][2]=mfma16(a3,b2,acc[3][2]); acc[3][3]=mfma16(a3,b3,acc[3][3]);    \
    __builtin_amdgcn_s_setprio(0);                                           \
    a0 = *(const bf16x8*)(Ab + offA[1][0]);                                  \
    a1 = *(const bf16x8*)(Ab + offA[1][1]);                                  \
    a2 = *(const bf16x8*)(Ab + offA[1][2]);                                  \
    a3 = *(const bf16x8*)(Ab + offA[1][3]);                                  \
    __builtin_amdgcn_s_setprio(1);                                           \
    acc[4][0]=mfma16(a0,b0,acc[4][0]); acc[4][1]=mfma16(a0,b1,acc[4][1]);    \
    acc[4][2]=mfma16(a0,b2,acc[4][2]); acc[4][3]=mfma16(a0,b3,acc[4][3]);    \
    acc[5][0]=mfma16(a1,b0,acc[5][0]); acc[5][1]=mfma16(a1,b1,acc[5][1]);    \
    acc[5][2]=mfma16(a1,b2,acc[5][2]); acc[5][3]=mfma16(a1,b3,acc[5][3]);    \
    acc[6][0]=mfma16(a2,b0,acc[6][0]); acc[6][1]=mfma16(a2,b1,acc[6][1]);    \
    acc[6][2]=mfma16(a2,b2,acc[6][2]); acc[6][3]=mfma16(a2,b3,acc[6][3]);    \
    acc[7][0]=mfma16(a3,b0,acc[7][0]); acc[7][1]=mfma16(a3,b1,acc[7][1]);    \
    acc[7][2]=mfma16(a3,b2,acc[7][2]); acc[7][3]=mfma16(a3,b3,acc[7][3]);    \
    __builtin_amdgcn_s_setprio(0); }

  // prologue: 3 K-tiles in flight
  QSTAGE(0); QSTAGE(1); QSTAGE(2);

#pragma unroll 1
  for (int kt = 0; kt < 29; ++kt) {
    QKTILE(kt, "8", 1);
  }
  QKTILE(29, "8", 0);
  QKTILE(30, "4", 0);
  QKTILE(31, "0", 0);
#undef QSTAGE
#undef QKTILE

  // ------------------------- epilogue ---------------------------------
  const int ft = m0 >> 8;                            // feature-tile 0..11
  if (ft < 8) {
    // Q/K: flash-verified relayout -> coalesced frag16x64 stores.
#pragma unroll
    for (int g = 0; g < 2; g++) {                    // 64-feature group
      const int fb = m0 + wr * 128 + g * 64;
      const bool isQ = (fb < Dc);
      unsigned short* const dstm = isQ ? Qf : Kf;
      const int head = (isQ ? fb : fb - Dc) >> 6;
      float4 b4[4];
#pragma unroll
      for (int mq = 0; mq < 4; mq++)
        b4[mq] = *(const float4*)(bias + fb + mq * 16 + lg * 4);
#pragma unroll
      for (int n = 0; n < 4; n++) {
        unsigned w8[4][2];
#pragma unroll
        for (int mq = 0; mq < 4; mq++) {
          float e0 = acc[g * 4 + mq][n][0] + b4[mq].x;
          float e1 = acc[g * 4 + mq][n][1] + b4[mq].y;
          float e2 = acc[g * 4 + mq][n][2] + b4[mq].z;
          float e3 = acc[g * 4 + mq][n][3] + b4[mq].w;
          if (isQ) {
            e0 *= 0.18033688f; e1 *= 0.18033688f;    // (1/8)*log2(e)
            e2 *= 0.18033688f; e3 *= 0.18033688f;
          }
          asm("v_cvt_pk_bf16_f32 %0, %1, %2" : "=v"(w8[mq][0]) : "v"(e0), "v"(e1));
          asm("v_cvt_pk_bf16_f32 %0, %1, %2" : "=v"(w8[mq][1]) : "v"(e2), "v"(e3));
        }
        const int t = n0 + wc * 64 + n * 16;         // token base (lr within)
        const int bb = t >> 11, tl = t & 2047;
        unsigned short* dst = dstm + (size_t)(bb * 16 + head) * 131072
                            + (tl >> 4) * 1024;
#pragma unroll
        for (int half = 0; half < 2; half++) {
          unsigned a0 = w8[2 * half][0], c0 = w8[2 * half + 1][0];
          unsigned a1 = w8[2 * half][1], c1 = w8[2 * half + 1][1];
          pl32swap(a0, c0);
          pl32swap(a1, c1);
          pl16swap(a0, c0);
          pl16swap(a1, c1);
          u32x4 w = { a0, a1, c0, c1 };
          *(u32x4*)(dst + half * 512 + lane * 8) = w;
        }
      }
    }
  } else {
    // V: scatter into V^T frag16x64 (verified path)
#pragma unroll
    for (int m = 0; m < 8; m++)
#pragma unroll
      for (int n = 0; n < 4; n++)
#pragma unroll
        for (int r = 0; r < 4; r++) {
          int f = m0 + wr * 128 + m * 16 + lg * 4 + r;
          int t = n0 + wc * 64 + n * 16 + lr;
          float v = acc[m][n][r] + bias[f];
          int c = f - 2 * Dc, head = c >> 6, d = c & 63;
          int bb = t >> 11, tl = t & 2047;
          Vf[(size_t)(bb * 16 + head) * 131072 + (tl >> 6) * 4096
             + fragaddr(d, tl & 63)] = f2bf(v);
        }
  }
}

// ---------------------------------------------------------------------------
// gemm_bt (verified 128x128 structure) -- output projection, fp32 out.
// ---------------------------------------------------------------------------
__global__ __launch_bounds__(256) void gemm_bt(const unsigned short* __restrict__ A,
                                               const unsigned short* __restrict__ Bt,
                                               const float* __restrict__ bias,
                                               float* __restrict__ Cout,
                                               int N, int K) {
  __shared__ unsigned short As[128 * 64];
  __shared__ unsigned short Bs[128 * 64];
  const int tid = threadIdx.x;
  const int lane = tid & 63, wid = tid >> 6;
  const int lr = lane & 15, lg = lane >> 4;
  const int wrow = wid >> 1, wcol = wid & 1;
  const int m0 = blockIdx.y * 128, n0 = blockIdx.x * 128;

  f32x4 acc[4][4] = {};

  for (int k0 = 0; k0 < K; k0 += 64) {
#pragma unroll
    for (int i = 0; i < 4; i++) {
      int ci = i * 256 + tid;
      int row = ci >> 3, ph = ci & 7;
      int cl = ph ^ (row & 7);
      gload_lds16(A + (size_t)(m0 + row) * K + k0 + cl * 8, As + (size_t)(i * 256 + wid * 64) * 8);
      gload_lds16(Bt + (size_t)(n0 + row) * K + k0 + cl * 8, Bs + (size_t)(i * 256 + wid * 64) * 8);
    }
    asm volatile("s_waitcnt vmcnt(0)" ::: "memory");
    __syncthreads();
#pragma unroll
    for (int kk = 0; kk < 2; kk++) {
      bf16x8 av[4], bv[4];
#pragma unroll
      for (int m = 0; m < 4; m++) {
        int row = wrow * 64 + m * 16 + lr;
        int ph = (kk * 4 + lg) ^ (row & 7);
        av[m] = *(const bf16x8*)(As + row * 64 + ph * 8);
      }
#pragma unroll
      for (int n = 0; n < 4; n++) {
        int row = wcol * 64 + n * 16 + lr;
        int ph = (kk * 4 + lg) ^ (row & 7);
        bv[n] = *(const bf16x8*)(Bs + row * 64 + ph * 8);
      }
#pragma unroll
      for (int m = 0; m < 4; m++)
#pragma unroll
        for (int n = 0; n < 4; n++)
          acc[m][n] = mfma16(av[m], bv[n], acc[m][n]);
    }
    __syncthreads();
  }

#pragma unroll
  for (int m = 0; m < 4; m++)
#pragma unroll
    for (int n = 0; n < 4; n++)
#pragma unroll
      for (int r = 0; r < 4; r++) {
        int row = m0 + wrow * 64 + m * 16 + lg * 4 + r;
        int col = n0 + wcol * 64 + n * 16 + lr;
        Cout[(size_t)row * N + col] = acc[m][n][r] + bias[col];
      }
}

// ---------------------------------------------------------------------------
// flash10: KV-split flash attention (round-15 body, numerically verified).
// Plain launch_bounds(512): compiler keeps ~124 VGPR (as flash8 proved for
// the identical body) -> no scratch spill; at <=128 VGPR the HW can schedule
// 2 blocks/CU = 4 waves/SIMD across the 512-block grid.
// Grid (8, 64) = 512 blocks x 8 waves = 4096 waves.
// ---------------------------------------------------------------------------
__global__ __launch_bounds__(512) void flash10(const unsigned short* __restrict__ Qf,
                                               const unsigned short* __restrict__ Kf,
                                               const unsigned short* __restrict__ Vf,
                                               const int* __restrict__ mask,
                                               unsigned short* __restrict__ Opart,
                                               unsigned short* __restrict__ Lpart) {
  const int tid = threadIdx.x;
  const int lane = tid & 63, wid = tid >> 6;   // wid 0..7
  const int lr = lane & 15, lg = lane >> 4;

  const int lin = blockIdx.y * 8 + blockIdx.x;      // 0..511
  const int swz = (lin & 7) * 64 + (lin >> 3);      // xcd = lin&7 -> 8 heads/XCD
  const int kvh = swz & 1, qb = (swz >> 1) & 3, bh = swz >> 3;
  const int b = bh >> 4, h = bh & 15;
  const int wq = qb * 512 + wid * 64;               // wave's q base

  const unsigned short* Qb = Qf + (size_t)bh * 131072;
  const unsigned short* Kb = Kf + (size_t)bh * 131072;
  const unsigned short* Vb = Vf + (size_t)bh * 131072;

  bf16x8 qf[4][2];
#pragma unroll
  for (int qn = 0; qn < 4; qn++)
#pragma unroll
    for (int kk = 0; kk < 2; kk++)
      qf[qn][kk] = *(const bf16x8*)(Qb + ((wq >> 4) + qn) * 1024 + kk * 512 + lane * 8);

  f32x4 o[4][4] = {};
  f32x4 lacc[4] = {};

  bf16x8 ones;
#pragma unroll
  for (int j = 0; j < 8; j++) ones[j] = (bf16_t)1.0f;

  // whole-mask all-ones check (8 coalesced int4 loads), hoisted
  bool allone = true;
#pragma unroll
  for (int j = 0; j < 8; j++) {
    int4 mv = ((const int4*)mask)[j * 64 + lane];
    allone = allone && (mv.x != 0) && (mv.y != 0) && (mv.z != 0) && (mv.w != 0);
  }
  const bool nomask = (__ballot(allone) == ~0ull);

  const int t0 = kvh * 16, t1 = t0 + 16;
#pragma unroll 2
  for (int tile = t0; tile < t1; tile++) {
    bf16x8 kf[4][2];
#pragma unroll
    for (int n = 0; n < 4; n++)
#pragma unroll
      for (int kk = 0; kk < 2; kk++)
        kf[n][kk] = *(const bf16x8*)(Kb + (tile * 4 + n) * 1024 + kk * 512 + lane * 8);
    bf16x8 vf[4][2];
#pragma unroll
    for (int dn = 0; dn < 4; dn++)
#pragma unroll
      for (int kk = 0; kk < 2; kk++)
        vf[dn][kk] = *(const bf16x8*)(Vb + tile * 4096 + dn * 1024 + kk * 512 + lane * 8);

    unsigned long long mb = ~0ull;
    if (!nomask) mb = __ballot(mask[tile * 64 + lane] != 0);

    unsigned pk[4][4][2];
#pragma unroll
    for (int kvn = 0; kvn < 4; kvn++) {
      f32x4 st[4] = {};
#pragma unroll
      for (int qn = 0; qn < 4; qn++) {
        st[qn] = mfma16(kf[kvn][0], qf[qn][0], st[qn]);
        st[qn] = mfma16(kf[kvn][1], qf[qn][1], st[qn]);
      }
      if (mb != ~0ull) {
#pragma unroll
        for (int r = 0; r < 4; r++)
          if (!((mb >> (kvn * 16 + lg * 4 + r)) & 1ull)) {
#pragma unroll
            for (int qn = 0; qn < 4; qn++) st[qn][r] = -1e30f;
          }
      }
#pragma unroll
      for (int qn = 0; qn < 4; qn++) {
        float e[4];
#pragma unroll
        for (int r = 0; r < 4; r++)
          asm("v_exp_f32 %0, %1" : "=v"(e[r]) : "v"(st[qn][r]));
        asm("v_cvt_pk_bf16_f32 %0, %1, %2" : "=v"(pk[qn][kvn][0]) : "v"(e[0]), "v"(e[1]));
        asm("v_cvt_pk_bf16_f32 %0, %1, %2" : "=v"(pk[qn][kvn][1]) : "v"(e[2]), "v"(e[3]));
      }
    }

    bf16x8 pa[4][2];
#pragma unroll
    for (int qn = 0; qn < 4; qn++)
#pragma unroll
      for (int m = 0; m < 2; m++) {
        unsigned a0 = pk[qn][2 * m][0], b0 = pk[qn][2 * m + 1][0];
        unsigned a1 = pk[qn][2 * m][1], b1 = pk[qn][2 * m + 1][1];
        pl32swap(a0, b0);
        pl32swap(a1, b1);
        pl16swap(a0, b0);
        pl16swap(a1, b1);
        u32x4 w = { a0, a1, b0, b1 };
        pa[qn][m] = __builtin_bit_cast(bf16x8, w);
      }

    __builtin_amdgcn_s_setprio(1);
#pragma unroll
    for (int qn = 0; qn < 4; qn++) {
#pragma unroll
      for (int dn = 0; dn < 4; dn++) {
        o[qn][dn] = mfma16(pa[qn][0], vf[dn][0], o[qn][dn]);
        o[qn][dn] = mfma16(pa[qn][1], vf[dn][1], o[qn][dn]);
      }
      lacc[qn] = mfma16(pa[qn][0], ones, lacc[qn]);
      lacc[qn] = mfma16(pa[qn][1], ones, lacc[qn]);
    }
    __builtin_amdgcn_s_setprio(0);
  }

  // epilogue: fp16 partial O in per-lane fragment layout (coalesced) + lacc.
  const int c = (bh * 4 + qb) * 8 + wid;            // 0..2047
  unsigned short* ob = Opart + (size_t)c * 8192 + kvh * 4096 + lane * 64;
#pragma unroll
  for (int qn = 0; qn < 4; qn++) {
    unsigned p[8];
#pragma unroll
    for (int dn = 0; dn < 4; dn++) {
      asm("v_cvt_pkrtz_f16_f32 %0, %1, %2" : "=v"(p[dn * 2]) : "v"(o[qn][dn][0]), "v"(o[qn][dn][1]));
      asm("v_cvt_pkrtz_f16_f32 %0, %1, %2" : "=v"(p[dn * 2 + 1]) : "v"(o[qn][dn][2]), "v"(o[qn][dn][3]));
    }
    u32x4 wlo = { p[0], p[1], p[2], p[3] };
    u32x4 whi = { p[4], p[5], p[6], p[7] };
    *(u32x4*)(ob + qn * 16) = wlo;
    *(u32x4*)(ob + qn * 16 + 8) = whi;
  }
  if (lr == 0) {
#pragma unroll
    for (int qn = 0; qn < 4; qn++)
#pragma unroll
      for (int r = 0; r < 4; r++) {
        int row = qn * 16 + lg * 4 + r;
        Lpart[(size_t)c * 128 + kvh * 64 + row] = f2h(lacc[qn][r]);
      }
  }
}

// ---------------------------------------------------------------------------
// reduce_o: merged = (o0 + o1) / (l0 + l1), decoded from fragment layout.
// 512 blocks x 256 threads; thread = (c, lane). (verified round-15)
// ---------------------------------------------------------------------------
__global__ __launch_bounds__(256) void reduce_o(const unsigned short* __restrict__ Opart,
                                                const unsigned short* __restrict__ Lpart,
                                                unsigned short* __restrict__ merged) {
  const int t = blockIdx.x * 256 + threadIdx.x;     // 0..131071
  const int c = t >> 6, lane = t & 63;
  const int bh = c >> 5, qb = (c >> 3) & 3, wid = c & 7;
  const int b = bh >> 4, h = bh & 15;
  const int lg = lane >> 4, lr = lane & 15;

  const unsigned short* o0 = Opart + (size_t)c * 8192 + lane * 64;
  const unsigned short* o1 = o0 + 4096;

  float linv[16];
#pragma unroll
  for (int qn = 0; qn < 4; qn++)
#pragma unroll
    for (int r = 0; r < 4; r++) {
      int row = qn * 16 + lg * 4 + r;
      float l0 = h2f(Lpart[(size_t)c * 128 + row]);
      float l1 = h2f(Lpart[(size_t)c * 128 + 64 + row]);
      linv[qn * 4 + r] = 1.0f / (l0 + l1);
    }

#pragma unroll
  for (int qn = 0; qn < 4; qn++) {
    u16x8 a0 = *(const u16x8*)(o0 + qn * 16);
    u16x8 a1 = *(const u16x8*)(o0 + qn * 16 + 8);
    u16x8 c0 = *(const u16x8*)(o1 + qn * 16);
    u16x8 c1 = *(const u16x8*)(o1 + qn * 16 + 8);
#pragma unroll
    for (int dn = 0; dn < 4; dn++)
#pragma unroll
      for (int r = 0; r < 4; r++) {
        int j = dn * 4 + r;
        unsigned short h0 = (j < 8) ? a0[j] : a1[j - 8];
        unsigned short h1 = (j < 8) ? c0[j] : c1[j - 8];
        float s = h2f(h0) + h2f(h1);
        int q = qb * 512 + wid * 64 + qn * 16 + lg * 4 + r;
        int d = dn * 16 + lr;
        merged[((size_t)(b * 2048 + q)) * 1024 + h * 64 + d] = f2bf(s * linv[qn * 4 + r]);
      }
  }
}

// ---------------------------------------------------------------------------
extern "C" void kernel_launch(void* const* d_in, const int* in_sizes, int n_in,
                              void* d_out, int out_size, void* d_ws, size_t ws_size,
                              hipStream_t stream) {
  const float* embed = (const float*)d_in[0];
  const int*   mask  = (const int*)d_in[1];
  const float* Wq = (const float*)d_in[2];
  const float* bq = (const float*)d_in[3];
  const float* Wk = (const float*)d_in[4];
  const float* bk = (const float*)d_in[5];
  const float* Wv = (const float*)d_in[6];
  const float* bv = (const float*)d_in[7];
  const float* Wo = (const float*)d_in[8];
  const float* bo = (const float*)d_in[9];
  float* out = (float*)d_out;

  char* ws = (char*)d_ws;
  unsigned short* WtAll  = (unsigned short*)ws; ws += (size_t)4 * Dc * Dc * 2;   //  8.4 MB
  unsigned short* Qf     = (unsigned short*)ws; ws += (size_t)Mc * Dc * 2;       // 16.8 MB
  unsigned short* Kf     = (unsigned short*)ws; ws += (size_t)Mc * Dc * 2;       // 16.8 MB
  unsigned short* Vf     = (unsigned short*)ws; ws += (size_t)Mc * Dc * 2;       // 16.8 MB
  unsigned short* merged = (unsigned short*)ws; ws += (size_t)Mc * Dc * 2;       // 16.8 MB
  unsigned short* embed_bf = (unsigned short*)ws;                                 // overlay base
  unsigned short* Opart    = embed_bf;          ws += (size_t)Mc * Dc * 2;       // 16.8 MB
  float*          ball     = (float*)ws;        ws += 16384;                     // 16 KB
  ws += (size_t)2048 * 8192 * 2 - ((size_t)Mc * Dc * 2 + 16384);
  unsigned short* Lpart  = (unsigned short*)ws; ws += (size_t)2048 * 128 * 2;    //  0.5 MB

  prep<<<8192 + 1024 + 1, 256, 0, stream>>>(embed, Wq, Wk, Wv, Wo, bq, bk, bv,
                                            embed_bf, WtAll, ball);
  gemm_qkv11<<<dim3(12, 32), 512, 0, stream>>>(WtAll, embed_bf, ball, Qf, Kf, Vf);
  flash10<<<dim3(8, 64), 512, 0, stream>>>(Qf, Kf, Vf, mask, Opart, Lpart);
  reduce_o<<<512, 256, 0, stream>>>(Opart, Lpart, merged);
  gemm_bt<<<dim3(8, 64), 256, 0, stream>>>(merged, WtAll + (size_t)3 * Dc * Dc, bo, out, Dc, Dc);
}

// Round 17
// 180.775 us; speedup vs baseline: 3.4772x; 1.1322x over previous
//
#include <hip/hip_runtime.h>

// ---------------------------------------------------------------------------
// SelfAttention (B=4,T=2048,D=1024,H=16,hd=64) fp32 in/out, bf16 MFMA compute.
// Pipeline (4 kernels): prep -> gemm_qkv11 (operand-swapped, permlane
// epilogue) -> flash11 (flash8 + per-wave KV start-offset desync) -> out gemm.
//
// frag16x64 layout: matrix [R][64] stored per 16-row block:
//   addr(row,col) = (row>>4)*1024 + (col>>5)*512 + ((col>>3)&3)*128
//                 + (row&15)*8 + (col&7)
// ---------------------------------------------------------------------------

typedef __bf16 bf16_t;
typedef bf16_t bf16x8 __attribute__((ext_vector_type(8)));
typedef float  f32x4  __attribute__((ext_vector_type(4)));
typedef unsigned u32x4 __attribute__((ext_vector_type(4)));
typedef unsigned short u16x8 __attribute__((ext_vector_type(8)));
typedef unsigned short u16x4 __attribute__((ext_vector_type(4)));

#define DEV static __device__ __forceinline__

constexpr int Bc = 4, Tc = 2048, Dc = 1024, Hc = 16, HDc = 64;
constexpr int Mc = Bc * Tc;        // 8192 rows
constexpr int NQKV = 3 * Dc;       // 3072

DEV unsigned short f2bf(float f) {
  union { float f; unsigned u; } v; v.f = f;
  return (unsigned short)((v.u + 0x7fffu + ((v.u >> 16) & 1u)) >> 16);
}

DEV void gload_lds16(const void* g, const void* ldsbase) {
  unsigned m0v = __builtin_amdgcn_readfirstlane((unsigned)(unsigned long long)ldsbase);
  asm volatile("s_mov_b32 m0, %0\n\t"
               "global_load_lds_dwordx4 %1, off"
               :: "s"(m0v), "v"(g) : "memory");
}

DEV f32x4 mfma16(bf16x8 a, bf16x8 b, f32x4 c) {
  return __builtin_amdgcn_mfma_f32_16x16x32_bf16(a, b, c, 0, 0, 0);
}

DEV void pl32swap(unsigned& a, unsigned& b) {
  asm("v_permlane32_swap_b32 %0, %1" : "+v"(a), "+v"(b));
}
DEV void pl16swap(unsigned& a, unsigned& b) {
  asm("v_permlane16_swap_b32 %0, %1" : "+v"(a), "+v"(b));
}

// frag16x64 element address (row within a [R][64] matrix)
DEV int fragaddr(int row, int col) {
  return (row >> 4) * 1024 + ((col >> 5) << 9) + (((col >> 3) & 3) << 7)
       + ((row & 15) << 3) + (col & 7);
}

// ---------------------------------------------------------------------------
// prep: fused cvt_embed (blocks 0..8191) + wt_cvt (8192..9215) + bias (9216)
// ---------------------------------------------------------------------------
__global__ __launch_bounds__(256) void prep(const float* __restrict__ embed,
                                            const float* __restrict__ Wq,
                                            const float* __restrict__ Wk,
                                            const float* __restrict__ Wv,
                                            const float* __restrict__ Wo,
                                            const float* __restrict__ bq,
                                            const float* __restrict__ bk,
                                            const float* __restrict__ bv,
                                            unsigned short* __restrict__ embed_bf,
                                            unsigned short* __restrict__ WtAll,
                                            float* __restrict__ ball) {
  __shared__ unsigned short tile[64 * 80];
  const int bb = blockIdx.x;
  const int tid = threadIdx.x;

  if (bb < 8192) {                                   // ---- embed f32 -> bf16
    int i = bb * 256 + tid;
    float4 v = ((const float4*)embed)[i];
    u16x4 o = { f2bf(v.x), f2bf(v.y), f2bf(v.z), f2bf(v.w) };
    *(u16x4*)(embed_bf + (size_t)i * 4) = o;
    return;
  }
  if (bb < 8192 + 1024) {                            // ---- W -> W^T bf16
    int wb = bb - 8192;
    int bx = wb & 15, by = (wb >> 4) & 15, bz = wb >> 8;
    const float* W = bz == 0 ? Wq : bz == 1 ? Wk : bz == 2 ? Wv : Wo;
    unsigned short* dst = WtAll + (size_t)bz * 1024 * 1024;
    const int kb = by * 64, nb = bx * 64;
#pragma unroll
    for (int i = 0; i < 4; i++) {
      int ci = i * 256 + tid;
      int r = ci >> 4, c4 = ci & 15;
      float4 v = *(const float4*)(W + (size_t)(kb + r) * 1024 + nb + c4 * 4);
      u16x4 o = { f2bf(v.x), f2bf(v.y), f2bf(v.z), f2bf(v.w) };
      *(u16x4*)(tile + r * 80 + c4 * 4) = o;
    }
    __syncthreads();
#pragma unroll
    for (int i = 0; i < 2; i++) {
      int ci = i * 256 + tid;
      int n = ci >> 3, c8 = ci & 7;
      u16x8 o;
#pragma unroll
      for (int j = 0; j < 8; j++) o[j] = tile[(c8 * 8 + j) * 80 + n];
      *(u16x8*)(dst + (size_t)(nb + n) * 1024 + kb + c8 * 8) = o;
    }
    return;
  }
  // ---- bias concat (single block)
#pragma unroll
  for (int it = 0; it < 12; it++) {
    int i = it * 256 + tid;
    ball[i] = (i < 1024) ? bq[i] : (i < 2048) ? bk[i - 1024] : bv[i - 2048];
  }
}

// ---------------------------------------------------------------------------
// gemm_qkv11 (verified round-13): operand-swapped QKV projection.
// ---------------------------------------------------------------------------
__global__ __launch_bounds__(512, 2) void gemm_qkv11(
    const unsigned short* __restrict__ Wt,     // WtAll    [3072][1024]
    const unsigned short* __restrict__ Eb,     // embed_bf [8192][1024]
    const float* __restrict__ bias,            // ball[3072]
    unsigned short* __restrict__ Qf,
    unsigned short* __restrict__ Kf,
    unsigned short* __restrict__ Vf) {
  __shared__ unsigned short As_[4 * 8192];     // 64 KB (Wt rows)
  __shared__ unsigned short Bs_[4 * 8192];     // 64 KB (embed rows)

  const int tid = threadIdx.x;
  const int lane = tid & 63, wid = tid >> 6;
  const int lr = lane & 15, lg = lane >> 4;
  const int wr = wid >> 2, wc = wid & 3;

  const int lin = blockIdx.y * 12 + blockIdx.x;        // 0..383
  const int swz = (lin & 7) * 48 + (lin >> 3);
  const int m0 = (swz % 12) * 256, n0 = (swz / 12) * 256;

  size_t gA[2], gB[2];
  int ldsoff[2];
#pragma unroll
  for (int i = 0; i < 2; i++) {
    int ci = i * 512 + tid;
    int row = ci >> 2;
    int cl = (ci & 3) ^ ((row ^ (row >> 2)) & 3);
    gA[i] = (size_t)(m0 + row) * 1024 + cl * 8;
    gB[i] = (size_t)(n0 + row) * 1024 + cl * 8;
    ldsoff[i] = ci * 8;
  }

  int offA[2][4], offB[4];
#pragma unroll
  for (int mq = 0; mq < 2; mq++)
#pragma unroll
    for (int m = 0; m < 4; m++) {
      int row = wr * 128 + mq * 64 + m * 16 + lr;
      offA[mq][m] = row * 32 + ((lg ^ ((row ^ (row >> 2)) & 3)) << 3);
    }
#pragma unroll
  for (int n = 0; n < 4; n++) {
    int row = wc * 64 + n * 16 + lr;
    offB[n] = row * 32 + ((lg ^ ((row ^ (row >> 2)) & 3)) << 3);
  }

  f32x4 acc[8][4] = {};

#define QSTAGE(kt) {                                                         \
    const int sbi_ = (kt) & 3;                                               \
    _Pragma("unroll")                                                        \
    for (int i_ = 0; i_ < 2; i_++) {                                         \
      gload_lds16(Wt + gA[i_] + (size_t)(kt) * 32,                           \
                  As_ + sbi_ * 8192 + ldsoff[i_]);                           \
      gload_lds16(Eb + gB[i_] + (size_t)(kt) * 32,                           \
                  Bs_ + sbi_ * 8192 + ldsoff[i_]);                           \
    } }

#define QKTILE(kt, VM, DOST) {                                               \
    const int bi_ = (kt) & 3;                                                \
    const unsigned short* Ab = As_ + bi_ * 8192;                             \
    const unsigned short* Bb = Bs_ + bi_ * 8192;                             \
    asm volatile("s_waitcnt vmcnt(" VM ")" ::: "memory");                    \
    asm volatile("s_barrier" ::: "memory");                                  \
    bf16x8 a0 = *(const bf16x8*)(Ab + offA[0][0]);                           \
    bf16x8 a1 = *(const bf16x8*)(Ab + offA[0][1]);                           \
    bf16x8 a2 = *(const bf16x8*)(Ab + offA[0][2]);                           \
    bf16x8 a3 = *(const bf16x8*)(Ab + offA[0][3]);                           \
    bf16x8 b0 = *(const bf16x8*)(Bb + offB[0]);                              \
    bf16x8 b1 = *(const bf16x8*)(Bb + offB[1]);                              \
    bf16x8 b2 = *(const bf16x8*)(Bb + offB[2]);                              \
    bf16x8 b3 = *(const bf16x8*)(Bb + offB[3]);                              \
    if (DOST) QSTAGE((kt) + 3);                                              \
    __builtin_amdgcn_s_setprio(1);                                           \
    acc[0][0]=mfma16(a0,b0,acc[0][0]); acc[0][1]=mfma16(a0,b1,acc[0][1]);    \
    acc[0][2]=mfma16(a0,b2,acc[0][2]); acc[0][3]=mfma16(a0,b3,acc[0][3]);    \
    acc[1][0]=mfma16(a1,b0,acc[1][0]); acc[1][1]=mfma16(a1,b1,acc[1][1]);    \
    acc[1][2]=mfma16(a1,b2,acc[1][2]); acc[1][3]=mfma16(a1,b3,acc[1][3]);    \
    acc[2][0]=mfma16(a2,b0,acc[2][0]); acc[2][1]=mfma16(a2,b1,acc[2][1]);    \
    acc[2][2]=mfma16(a2,b2,acc[2][2]); acc[2][3]=mfma16(a2,b3,acc[2][3]);    \
    acc[3][0]=mfma16(a3,b0,acc[3][0]); acc[3][1]=mfma16(a3,b1,acc[3][1]);    \
    acc[3][2]=mfma16(a3,b2,acc[3][2]); acc[3][3]=mfma16(a3,b3,acc[3][3]);    \
    __builtin_amdgcn_s_setprio(0);                                           \
    a0 = *(const bf16x8*)(Ab + offA[1][0]);                                  \
    a1 = *(const bf16x8*)(Ab + offA[1][1]);                                  \
    a2 = *(const bf16x8*)(Ab + offA[1][2]);                                  \
    a3 = *(const bf16x8*)(Ab + offA[1][3]);                                  \
    __builtin_amdgcn_s_setprio(1);                                           \
    acc[4][0]=mfma16(a0,b0,acc[4][0]); acc[4][1]=mfma16(a0,b1,acc[4][1]);    \
    acc[4][2]=mfma16(a0,b2,acc[4][2]); acc[4][3]=mfma16(a0,b3,acc[4][3]);    \
    acc[5][0]=mfma16(a1,b0,acc[5][0]); acc[5][1]=mfma16(a1,b1,acc[5][1]);    \
    acc[5][2]=mfma16(a1,b2,acc[5][2]); acc[5][3]=mfma16(a1,b3,acc[5][3]);    \
    acc[6][0]=mfma16(a2,b0,acc[6][0]); acc[6][1]=mfma16(a2,b1,acc[6][1]);    \
    acc[6][2]=mfma16(a2,b2,acc[6][2]); acc[6][3]=mfma16(a2,b3,acc[6][3]);    \
    acc[7][0]=mfma16(a3,b0,acc[7][0]); acc[7][1]=mfma16(a3,b1,acc[7][1]);    \
    acc[7][2]=mfma16(a3,b2,acc[7][2]); acc[7][3]=mfma16(a3,b3,acc[7][3]);    \
    __builtin_amdgcn_s_setprio(0); }

  // prologue: 3 K-tiles in flight
  QSTAGE(0); QSTAGE(1); QSTAGE(2);

#pragma unroll 1
  for (int kt = 0; kt < 29; ++kt) {
    QKTILE(kt, "8", 1);
  }
  QKTILE(29, "8", 0);
  QKTILE(30, "4", 0);
  QKTILE(31, "0", 0);
#undef QSTAGE
#undef QKTILE

  // ------------------------- epilogue ---------------------------------
  const int ft = m0 >> 8;                            // feature-tile 0..11
  if (ft < 8) {
    // Q/K: flash-verified relayout -> coalesced frag16x64 stores.
#pragma unroll
    for (int g = 0; g < 2; g++) {                    // 64-feature group
      const int fb = m0 + wr * 128 + g * 64;
      const bool isQ = (fb < Dc);
      unsigned short* const dstm = isQ ? Qf : Kf;
      const int head = (isQ ? fb : fb - Dc) >> 6;
      float4 b4[4];
#pragma unroll
      for (int mq = 0; mq < 4; mq++)
        b4[mq] = *(const float4*)(bias + fb + mq * 16 + lg * 4);
#pragma unroll
      for (int n = 0; n < 4; n++) {
        unsigned w8[4][2];
#pragma unroll
        for (int mq = 0; mq < 4; mq++) {
          float e0 = acc[g * 4 + mq][n][0] + b4[mq].x;
          float e1 = acc[g * 4 + mq][n][1] + b4[mq].y;
          float e2 = acc[g * 4 + mq][n][2] + b4[mq].z;
          float e3 = acc[g * 4 + mq][n][3] + b4[mq].w;
          if (isQ) {
            e0 *= 0.18033688f; e1 *= 0.18033688f;    // (1/8)*log2(e)
            e2 *= 0.18033688f; e3 *= 0.18033688f;
          }
          asm("v_cvt_pk_bf16_f32 %0, %1, %2" : "=v"(w8[mq][0]) : "v"(e0), "v"(e1));
          asm("v_cvt_pk_bf16_f32 %0, %1, %2" : "=v"(w8[mq][1]) : "v"(e2), "v"(e3));
        }
        const int t = n0 + wc * 64 + n * 16;         // token base (lr within)
        const int bb = t >> 11, tl = t & 2047;
        unsigned short* dst = dstm + (size_t)(bb * 16 + head) * 131072
                            + (tl >> 4) * 1024;
#pragma unroll
        for (int half = 0; half < 2; half++) {
          unsigned a0 = w8[2 * half][0], c0 = w8[2 * half + 1][0];
          unsigned a1 = w8[2 * half][1], c1 = w8[2 * half + 1][1];
          pl32swap(a0, c0);
          pl32swap(a1, c1);
          pl16swap(a0, c0);
          pl16swap(a1, c1);
          u32x4 w = { a0, a1, c0, c1 };
          *(u32x4*)(dst + half * 512 + lane * 8) = w;
        }
      }
    }
  } else {
    // V: scatter into V^T frag16x64 (verified path)
#pragma unroll
    for (int m = 0; m < 8; m++)
#pragma unroll
      for (int n = 0; n < 4; n++)
#pragma unroll
        for (int r = 0; r < 4; r++) {
          int f = m0 + wr * 128 + m * 16 + lg * 4 + r;
          int t = n0 + wc * 64 + n * 16 + lr;
          float v = acc[m][n][r] + bias[f];
          int c = f - 2 * Dc, head = c >> 6, d = c & 63;
          int bb = t >> 11, tl = t & 2047;
          Vf[(size_t)(bb * 16 + head) * 131072 + (tl >> 6) * 4096
             + fragaddr(d, tl & 63)] = f2bf(v);
        }
  }
}

// ---------------------------------------------------------------------------
// gemm_bt (verified 128x128 structure) -- output projection, fp32 out.
// ---------------------------------------------------------------------------
__global__ __launch_bounds__(256) void gemm_bt(const unsigned short* __restrict__ A,
                                               const unsigned short* __restrict__ Bt,
                                               const float* __restrict__ bias,
                                               float* __restrict__ Cout,
                                               int N, int K) {
  __shared__ unsigned short As[128 * 64];
  __shared__ unsigned short Bs[128 * 64];
  const int tid = threadIdx.x;
  const int lane = tid & 63, wid = tid >> 6;
  const int lr = lane & 15, lg = lane >> 4;
  const int wrow = wid >> 1, wcol = wid & 1;
  const int m0 = blockIdx.y * 128, n0 = blockIdx.x * 128;

  f32x4 acc[4][4] = {};

  for (int k0 = 0; k0 < K; k0 += 64) {
#pragma unroll
    for (int i = 0; i < 4; i++) {
      int ci = i * 256 + tid;
      int row = ci >> 3, ph = ci & 7;
      int cl = ph ^ (row & 7);
      gload_lds16(A + (size_t)(m0 + row) * K + k0 + cl * 8, As + (size_t)(i * 256 + wid * 64) * 8);
      gload_lds16(Bt + (size_t)(n0 + row) * K + k0 + cl * 8, Bs + (size_t)(i * 256 + wid * 64) * 8);
    }
    asm volatile("s_waitcnt vmcnt(0)" ::: "memory");
    __syncthreads();
#pragma unroll
    for (int kk = 0; kk < 2; kk++) {
      bf16x8 av[4], bv[4];
#pragma unroll
      for (int m = 0; m < 4; m++) {
        int row = wrow * 64 + m * 16 + lr;
        int ph = (kk * 4 + lg) ^ (row & 7);
        av[m] = *(const bf16x8*)(As + row * 64 + ph * 8);
      }
#pragma unroll
      for (int n = 0; n < 4; n++) {
        int row = wcol * 64 + n * 16 + lr;
        int ph = (kk * 4 + lg) ^ (row & 7);
        bv[n] = *(const bf16x8*)(Bs + row * 64 + ph * 8);
      }
#pragma unroll
      for (int m = 0; m < 4; m++)
#pragma unroll
        for (int n = 0; n < 4; n++)
          acc[m][n] = mfma16(av[m], bv[n], acc[m][n]);
    }
    __syncthreads();
  }

#pragma unroll
  for (int m = 0; m < 4; m++)
#pragma unroll
    for (int n = 0; n < 4; n++)
#pragma unroll
      for (int r = 0; r < 4; r++) {
        int row = m0 + wrow * 64 + m * 16 + lg * 4 + r;
        int col = n0 + wcol * 64 + n * 16 + lr;
        Cout[(size_t)row * N + col] = acc[m][n][r] + bias[col];
      }
}

// ---------------------------------------------------------------------------
// flash11: flash8 body with per-wave KV start-offset (tt = (tile + wid*4)&31).
// Exact softmax => accumulation order over KV tiles is irrelevant, so waves
// can sweep KV rotated. SIMD-mates (wid, wid+4) are 16 tiles apart -> one
// wave's QK-MFMA overlaps the other's softmax-VALU (phase desync, T5/m114).
// 8-wave (512-thread) blocks; grid (4 qb, 64 bh) = 256 blocks; XCD swizzle.
// ---------------------------------------------------------------------------
__global__ __launch_bounds__(512) void flash11(const unsigned short* __restrict__ Qf,
                                               const unsigned short* __restrict__ Kf,
                                               const unsigned short* __restrict__ Vf,
                                               const int* __restrict__ mask,
                                               unsigned short* __restrict__ merged) {
  const int tid = threadIdx.x;
  const int lane = tid & 63, wid = tid >> 6;   // wid 0..7
  const int lr = lane & 15, lg = lane >> 4;

  const int lin = blockIdx.y * 4 + blockIdx.x;      // 0..255
  const int swz = (lin & 7) * 32 + (lin >> 3);
  const int qb = swz & 3, bh = swz >> 2;
  const int b = bh >> 4, h = bh & 15;
  const int wq = qb * 512 + wid * 64;               // wave's q base

  const unsigned short* Qb = Qf + (size_t)bh * 131072;
  const unsigned short* Kb = Kf + (size_t)bh * 131072;
  const unsigned short* Vb = Vf + (size_t)bh * 131072;

  bf16x8 qf[4][2];
#pragma unroll
  for (int qn = 0; qn < 4; qn++)
#pragma unroll
    for (int kk = 0; kk < 2; kk++)
      qf[qn][kk] = *(const bf16x8*)(Qb + ((wq >> 4) + qn) * 1024 + kk * 512 + lane * 8);

  f32x4 o[4][4] = {};
  f32x4 lacc[4] = {};

  bf16x8 ones;
#pragma unroll
  for (int j = 0; j < 8; j++) ones[j] = (bf16_t)1.0f;

  // whole-mask all-ones check (8 coalesced int4 loads), hoisted
  bool allone = true;
#pragma unroll
  for (int j = 0; j < 8; j++) {
    int4 mv = ((const int4*)mask)[j * 64 + lane];
    allone = allone && (mv.x != 0) && (mv.y != 0) && (mv.z != 0) && (mv.w != 0);
  }
  const bool nomask = (__ballot(allone) == ~0ull);

  const int toff = wid * 4;                         // per-wave KV rotation
#pragma unroll 2
  for (int tile = 0; tile < 32; tile++) {
    const int tt = (tile + toff) & 31;
    bf16x8 kf[4][2];
#pragma unroll
    for (int n = 0; n < 4; n++)
#pragma unroll
      for (int kk = 0; kk < 2; kk++)
        kf[n][kk] = *(const bf16x8*)(Kb + (tt * 4 + n) * 1024 + kk * 512 + lane * 8);
    bf16x8 vf[4][2];
#pragma unroll
    for (int dn = 0; dn < 4; dn++)
#pragma unroll
      for (int kk = 0; kk < 2; kk++)
        vf[dn][kk] = *(const bf16x8*)(Vb + tt * 4096 + dn * 1024 + kk * 512 + lane * 8);

    unsigned long long mb = ~0ull;
    if (!nomask) mb = __ballot(mask[tt * 64 + lane] != 0);

    unsigned pk[4][4][2];
#pragma unroll
    for (int kvn = 0; kvn < 4; kvn++) {
      f32x4 st[4] = {};
#pragma unroll
      for (int qn = 0; qn < 4; qn++) {
        st[qn] = mfma16(kf[kvn][0], qf[qn][0], st[qn]);
        st[qn] = mfma16(kf[kvn][1], qf[qn][1], st[qn]);
      }
      if (mb != ~0ull) {
#pragma unroll
        for (int r = 0; r < 4; r++)
          if (!((mb >> (kvn * 16 + lg * 4 + r)) & 1ull)) {
#pragma unroll
            for (int qn = 0; qn < 4; qn++) st[qn][r] = -1e30f;
          }
      }
#pragma unroll
      for (int qn = 0; qn < 4; qn++) {
        float e[4];
#pragma unroll
        for (int r = 0; r < 4; r++)
          asm("v_exp_f32 %0, %1" : "=v"(e[r]) : "v"(st[qn][r]));
        asm("v_cvt_pk_bf16_f32 %0, %1, %2" : "=v"(pk[qn][kvn][0]) : "v"(e[0]), "v"(e[1]));
        asm("v_cvt_pk_bf16_f32 %0, %1, %2" : "=v"(pk[qn][kvn][1]) : "v"(e[2]), "v"(e[3]));
      }
    }

    bf16x8 pa[4][2];
#pragma unroll
    for (int qn = 0; qn < 4; qn++)
#pragma unroll
      for (int m = 0; m < 2; m++) {
        unsigned a0 = pk[qn][2 * m][0], b0 = pk[qn][2 * m + 1][0];
        unsigned a1 = pk[qn][2 * m][1], b1 = pk[qn][2 * m + 1][1];
        pl32swap(a0, b0);
        pl32swap(a1, b1);
        pl16swap(a0, b0);
        pl16swap(a1, b1);
        u32x4 w = { a0, a1, b0, b1 };
        pa[qn][m] = __builtin_bit_cast(bf16x8, w);
      }

    __builtin_amdgcn_s_setprio(1);
#pragma unroll
    for (int qn = 0; qn < 4; qn++) {
#pragma unroll
      for (int dn = 0; dn < 4; dn++) {
        o[qn][dn] = mfma16(pa[qn][0], vf[dn][0], o[qn][dn]);
        o[qn][dn] = mfma16(pa[qn][1], vf[dn][1], o[qn][dn]);
      }
      lacc[qn] = mfma16(pa[qn][0], ones, lacc[qn]);
      lacc[qn] = mfma16(pa[qn][1], ones, lacc[qn]);
    }
    __builtin_amdgcn_s_setprio(0);
  }

  // epilogue: normalize and store
#pragma unroll
  for (int qn = 0; qn < 4; qn++)
#pragma unroll
    for (int r = 0; r < 4; r++) {
      float inv = 1.0f / lacc[qn][r];
      int grow = b * Tc + wq + qn * 16 + lg * 4 + r;
#pragma unroll
      for (int dn = 0; dn < 4; dn++) {
        int gcol = h * HDc + dn * 16 + lr;
        merged[(size_t)grow * Dc + gcol] = f2bf(o[qn][dn][r] * inv);
      }
    }
}

// ---------------------------------------------------------------------------
extern "C" void kernel_launch(void* const* d_in, const int* in_sizes, int n_in,
                              void* d_out, int out_size, void* d_ws, size_t ws_size,
                              hipStream_t stream) {
  const float* embed = (const float*)d_in[0];
  const int*   mask  = (const int*)d_in[1];
  const float* Wq = (const float*)d_in[2];
  const float* bq = (const float*)d_in[3];
  const float* Wk = (const float*)d_in[4];
  const float* bk = (const float*)d_in[5];
  const float* Wv = (const float*)d_in[6];
  const float* bv = (const float*)d_in[7];
  const float* Wo = (const float*)d_in[8];
  const float* bo = (const float*)d_in[9];
  float* out = (float*)d_out;

  char* ws = (char*)d_ws;
  unsigned short* embed_bf = (unsigned short*)ws; ws += (size_t)Mc * Dc * 2;        // 16.8 MB
  unsigned short* WtAll    = (unsigned short*)ws; ws += (size_t)4 * Dc * Dc * 2;    //  8.4 MB
  float*          ball     = (float*)ws;          ws += 16384;
  unsigned short* Qf       = (unsigned short*)ws; ws += (size_t)Mc * Dc * 2;        // 16.8 MB
  unsigned short* Kf       = (unsigned short*)ws; ws += (size_t)Mc * Dc * 2;        // 16.8 MB
  unsigned short* Vf       = (unsigned short*)ws; ws += (size_t)Mc * Dc * 2;        // 16.8 MB
  unsigned short* merged   = (unsigned short*)ws; ws += (size_t)Mc * Dc * 2;        // 16.8 MB

  prep<<<8192 + 1024 + 1, 256, 0, stream>>>(embed, Wq, Wk, Wv, Wo, bq, bk, bv,
                                            embed_bf, WtAll, ball);
  gemm_qkv11<<<dim3(12, 32), 512, 0, stream>>>(WtAll, embed_bf, ball, Qf, Kf, Vf);
  flash11<<<dim3(4, 64), 512, 0, stream>>>(Qf, Kf, Vf, mask, merged);
  gemm_bt<<<dim3(8, 64), 256, 0, stream>>>(merged, WtAll + (size_t)3 * Dc * Dc, bo, out, Dc, Dc);
}

// Round 18
// 177.602 us; speedup vs baseline: 3.5393x; 1.0179x over previous
//
#include <hip/hip_runtime.h>

// ---------------------------------------------------------------------------
// SelfAttention (B=4,T=2048,D=1024,H=16,hd=64) fp32 in/out, bf16 MFMA compute.
// Pipeline (4 kernels): prep -> gemm_qkv11 (operand-swapped, permlane
// epilogue) -> flash12 (flash8 body, unroll-4 tile loop for 2-3-deep
// register prefetch) -> out gemm.
//
// frag16x64 layout: matrix [R][64] stored per 16-row block:
//   addr(row,col) = (row>>4)*1024 + (col>>5)*512 + ((col>>3)&3)*128
//                 + (row&15)*8 + (col&7)
// ---------------------------------------------------------------------------

typedef __bf16 bf16_t;
typedef bf16_t bf16x8 __attribute__((ext_vector_type(8)));
typedef float  f32x4  __attribute__((ext_vector_type(4)));
typedef unsigned u32x4 __attribute__((ext_vector_type(4)));
typedef unsigned short u16x8 __attribute__((ext_vector_type(8)));
typedef unsigned short u16x4 __attribute__((ext_vector_type(4)));

#define DEV static __device__ __forceinline__

constexpr int Bc = 4, Tc = 2048, Dc = 1024, Hc = 16, HDc = 64;
constexpr int Mc = Bc * Tc;        // 8192 rows
constexpr int NQKV = 3 * Dc;       // 3072

DEV unsigned short f2bf(float f) {
  union { float f; unsigned u; } v; v.f = f;
  return (unsigned short)((v.u + 0x7fffu + ((v.u >> 16) & 1u)) >> 16);
}

DEV void gload_lds16(const void* g, const void* ldsbase) {
  unsigned m0v = __builtin_amdgcn_readfirstlane((unsigned)(unsigned long long)ldsbase);
  asm volatile("s_mov_b32 m0, %0\n\t"
               "global_load_lds_dwordx4 %1, off"
               :: "s"(m0v), "v"(g) : "memory");
}

DEV f32x4 mfma16(bf16x8 a, bf16x8 b, f32x4 c) {
  return __builtin_amdgcn_mfma_f32_16x16x32_bf16(a, b, c, 0, 0, 0);
}

DEV void pl32swap(unsigned& a, unsigned& b) {
  asm("v_permlane32_swap_b32 %0, %1" : "+v"(a), "+v"(b));
}
DEV void pl16swap(unsigned& a, unsigned& b) {
  asm("v_permlane16_swap_b32 %0, %1" : "+v"(a), "+v"(b));
}

// frag16x64 element address (row within a [R][64] matrix)
DEV int fragaddr(int row, int col) {
  return (row >> 4) * 1024 + ((col >> 5) << 9) + (((col >> 3) & 3) << 7)
       + ((row & 15) << 3) + (col & 7);
}

// ---------------------------------------------------------------------------
// prep: fused cvt_embed (blocks 0..8191) + wt_cvt (8192..9215) + bias (9216)
// ---------------------------------------------------------------------------
__global__ __launch_bounds__(256) void prep(const float* __restrict__ embed,
                                            const float* __restrict__ Wq,
                                            const float* __restrict__ Wk,
                                            const float* __restrict__ Wv,
                                            const float* __restrict__ Wo,
                                            const float* __restrict__ bq,
                                            const float* __restrict__ bk,
                                            const float* __restrict__ bv,
                                            unsigned short* __restrict__ embed_bf,
                                            unsigned short* __restrict__ WtAll,
                                            float* __restrict__ ball) {
  __shared__ unsigned short tile[64 * 80];
  const int bb = blockIdx.x;
  const int tid = threadIdx.x;

  if (bb < 8192) {                                   // ---- embed f32 -> bf16
    int i = bb * 256 + tid;
    float4 v = ((const float4*)embed)[i];
    u16x4 o = { f2bf(v.x), f2bf(v.y), f2bf(v.z), f2bf(v.w) };
    *(u16x4*)(embed_bf + (size_t)i * 4) = o;
    return;
  }
  if (bb < 8192 + 1024) {                            // ---- W -> W^T bf16
    int wb = bb - 8192;
    int bx = wb & 15, by = (wb >> 4) & 15, bz = wb >> 8;
    const float* W = bz == 0 ? Wq : bz == 1 ? Wk : bz == 2 ? Wv : Wo;
    unsigned short* dst = WtAll + (size_t)bz * 1024 * 1024;
    const int kb = by * 64, nb = bx * 64;
#pragma unroll
    for (int i = 0; i < 4; i++) {
      int ci = i * 256 + tid;
      int r = ci >> 4, c4 = ci & 15;
      float4 v = *(const float4*)(W + (size_t)(kb + r) * 1024 + nb + c4 * 4);
      u16x4 o = { f2bf(v.x), f2bf(v.y), f2bf(v.z), f2bf(v.w) };
      *(u16x4*)(tile + r * 80 + c4 * 4) = o;
    }
    __syncthreads();
#pragma unroll
    for (int i = 0; i < 2; i++) {
      int ci = i * 256 + tid;
      int n = ci >> 3, c8 = ci & 7;
      u16x8 o;
#pragma unroll
      for (int j = 0; j < 8; j++) o[j] = tile[(c8 * 8 + j) * 80 + n];
      *(u16x8*)(dst + (size_t)(nb + n) * 1024 + kb + c8 * 8) = o;
    }
    return;
  }
  // ---- bias concat (single block)
#pragma unroll
  for (int it = 0; it < 12; it++) {
    int i = it * 256 + tid;
    ball[i] = (i < 1024) ? bq[i] : (i < 2048) ? bk[i - 1024] : bv[i - 2048];
  }
}

// ---------------------------------------------------------------------------
// gemm_qkv11 (verified round-13): operand-swapped QKV projection.
// ---------------------------------------------------------------------------
__global__ __launch_bounds__(512, 2) void gemm_qkv11(
    const unsigned short* __restrict__ Wt,     // WtAll    [3072][1024]
    const unsigned short* __restrict__ Eb,     // embed_bf [8192][1024]
    const float* __restrict__ bias,            // ball[3072]
    unsigned short* __restrict__ Qf,
    unsigned short* __restrict__ Kf,
    unsigned short* __restrict__ Vf) {
  __shared__ unsigned short As_[4 * 8192];     // 64 KB (Wt rows)
  __shared__ unsigned short Bs_[4 * 8192];     // 64 KB (embed rows)

  const int tid = threadIdx.x;
  const int lane = tid & 63, wid = tid >> 6;
  const int lr = lane & 15, lg = lane >> 4;
  const int wr = wid >> 2, wc = wid & 3;

  const int lin = blockIdx.y * 12 + blockIdx.x;        // 0..383
  const int swz = (lin & 7) * 48 + (lin >> 3);
  const int m0 = (swz % 12) * 256, n0 = (swz / 12) * 256;

  size_t gA[2], gB[2];
  int ldsoff[2];
#pragma unroll
  for (int i = 0; i < 2; i++) {
    int ci = i * 512 + tid;
    int row = ci >> 2;
    int cl = (ci & 3) ^ ((row ^ (row >> 2)) & 3);
    gA[i] = (size_t)(m0 + row) * 1024 + cl * 8;
    gB[i] = (size_t)(n0 + row) * 1024 + cl * 8;
    ldsoff[i] = ci * 8;
  }

  int offA[2][4], offB[4];
#pragma unroll
  for (int mq = 0; mq < 2; mq++)
#pragma unroll
    for (int m = 0; m < 4; m++) {
      int row = wr * 128 + mq * 64 + m * 16 + lr;
      offA[mq][m] = row * 32 + ((lg ^ ((row ^ (row >> 2)) & 3)) << 3);
    }
#pragma unroll
  for (int n = 0; n < 4; n++) {
    int row = wc * 64 + n * 16 + lr;
    offB[n] = row * 32 + ((lg ^ ((row ^ (row >> 2)) & 3)) << 3);
  }

  f32x4 acc[8][4] = {};

#define QSTAGE(kt) {                                                         \
    const int sbi_ = (kt) & 3;                                               \
    _Pragma("unroll")                                                        \
    for (int i_ = 0; i_ < 2; i_++) {                                         \
      gload_lds16(Wt + gA[i_] + (size_t)(kt) * 32,                           \
                  As_ + sbi_ * 8192 + ldsoff[i_]);                           \
      gload_lds16(Eb + gB[i_] + (size_t)(kt) * 32,                           \
                  Bs_ + sbi_ * 8192 + ldsoff[i_]);                           \
    } }

#define QKTILE(kt, VM, DOST) {                                               \
    const int bi_ = (kt) & 3;                                                \
    const unsigned short* Ab = As_ + bi_ * 8192;                             \
    const unsigned short* Bb = Bs_ + bi_ * 8192;                             \
    asm volatile("s_waitcnt vmcnt(" VM ")" ::: "memory");                    \
    asm volatile("s_barrier" ::: "memory");                                  \
    bf16x8 a0 = *(const bf16x8*)(Ab + offA[0][0]);                           \
    bf16x8 a1 = *(const bf16x8*)(Ab + offA[0][1]);                           \
    bf16x8 a2 = *(const bf16x8*)(Ab + offA[0][2]);                           \
    bf16x8 a3 = *(const bf16x8*)(Ab + offA[0][3]);                           \
    bf16x8 b0 = *(const bf16x8*)(Bb + offB[0]);                              \
    bf16x8 b1 = *(const bf16x8*)(Bb + offB[1]);                              \
    bf16x8 b2 = *(const bf16x8*)(Bb + offB[2]);                              \
    bf16x8 b3 = *(const bf16x8*)(Bb + offB[3]);                              \
    if (DOST) QSTAGE((kt) + 3);                                              \
    __builtin_amdgcn_s_setprio(1);                                           \
    acc[0][0]=mfma16(a0,b0,acc[0][0]); acc[0][1]=mfma16(a0,b1,acc[0][1]);    \
    acc[0][2]=mfma16(a0,b2,acc[0][2]); acc[0][3]=mfma16(a0,b3,acc[0][3]);    \
    acc[1][0]=mfma16(a1,b0,acc[1][0]); acc[1][1]=mfma16(a1,b1,acc[1][1]);    \
    acc[1][2]=mfma16(a1,b2,acc[1][2]); acc[1][3]=mfma16(a1,b3,acc[1][3]);    \
    acc[2][0]=mfma16(a2,b0,acc[2][0]); acc[2][1]=mfma16(a2,b1,acc[2][1]);    \
    acc[2][2]=mfma16(a2,b2,acc[2][2]); acc[2][3]=mfma16(a2,b3,acc[2][3]);    \
    acc[3][0]=mfma16(a3,b0,acc[3][0]); acc[3][1]=mfma16(a3,b1,acc[3][1]);    \
    acc[3][2]=mfma16(a3,b2,acc[3][2]); acc[3][3]=mfma16(a3,b3,acc[3][3]);    \
    __builtin_amdgcn_s_setprio(0);                                           \
    a0 = *(const bf16x8*)(Ab + offA[1][0]);                                  \
    a1 = *(const bf16x8*)(Ab + offA[1][1]);                                  \
    a2 = *(const bf16x8*)(Ab + offA[1][2]);                                  \
    a3 = *(const bf16x8*)(Ab + offA[1][3]);                                  \
    __builtin_amdgcn_s_setprio(1);                                           \
    acc[4][0]=mfma16(a0,b0,acc[4][0]); acc[4][1]=mfma16(a0,b1,acc[4][1]);    \
    acc[4][2]=mfma16(a0,b2,acc[4][2]); acc[4][3]=mfma16(a0,b3,acc[4][3]);    \
    acc[5][0]=mfma16(a1,b0,acc[5][0]); acc[5][1]=mfma16(a1,b1,acc[5][1]);    \
    acc[5][2]=mfma16(a1,b2,acc[5][2]); acc[5][3]=mfma16(a1,b3,acc[5][3]);    \
    acc[6][0]=mfma16(a2,b0,acc[6][0]); acc[6][1]=mfma16(a2,b1,acc[6][1]);    \
    acc[6][2]=mfma16(a2,b2,acc[6][2]); acc[6][3]=mfma16(a2,b3,acc[6][3]);    \
    acc[7][0]=mfma16(a3,b0,acc[7][0]); acc[7][1]=mfma16(a3,b1,acc[7][1]);    \
    acc[7][2]=mfma16(a3,b2,acc[7][2]); acc[7][3]=mfma16(a3,b3,acc[7][3]);    \
    __builtin_amdgcn_s_setprio(0); }

  // prologue: 3 K-tiles in flight
  QSTAGE(0); QSTAGE(1); QSTAGE(2);

#pragma unroll 1
  for (int kt = 0; kt < 29; ++kt) {
    QKTILE(kt, "8", 1);
  }
  QKTILE(29, "8", 0);
  QKTILE(30, "4", 0);
  QKTILE(31, "0", 0);
#undef QSTAGE
#undef QKTILE

  // ------------------------- epilogue ---------------------------------
  const int ft = m0 >> 8;                            // feature-tile 0..11
  if (ft < 8) {
    // Q/K: flash-verified relayout -> coalesced frag16x64 stores.
#pragma unroll
    for (int g = 0; g < 2; g++) {                    // 64-feature group
      const int fb = m0 + wr * 128 + g * 64;
      const bool isQ = (fb < Dc);
      unsigned short* const dstm = isQ ? Qf : Kf;
      const int head = (isQ ? fb : fb - Dc) >> 6;
      float4 b4[4];
#pragma unroll
      for (int mq = 0; mq < 4; mq++)
        b4[mq] = *(const float4*)(bias + fb + mq * 16 + lg * 4);
#pragma unroll
      for (int n = 0; n < 4; n++) {
        unsigned w8[4][2];
#pragma unroll
        for (int mq = 0; mq < 4; mq++) {
          float e0 = acc[g * 4 + mq][n][0] + b4[mq].x;
          float e1 = acc[g * 4 + mq][n][1] + b4[mq].y;
          float e2 = acc[g * 4 + mq][n][2] + b4[mq].z;
          float e3 = acc[g * 4 + mq][n][3] + b4[mq].w;
          if (isQ) {
            e0 *= 0.18033688f; e1 *= 0.18033688f;    // (1/8)*log2(e)
            e2 *= 0.18033688f; e3 *= 0.18033688f;
          }
          asm("v_cvt_pk_bf16_f32 %0, %1, %2" : "=v"(w8[mq][0]) : "v"(e0), "v"(e1));
          asm("v_cvt_pk_bf16_f32 %0, %1, %2" : "=v"(w8[mq][1]) : "v"(e2), "v"(e3));
        }
        const int t = n0 + wc * 64 + n * 16;         // token base (lr within)
        const int bb = t >> 11, tl = t & 2047;
        unsigned short* dst = dstm + (size_t)(bb * 16 + head) * 131072
                            + (tl >> 4) * 1024;
#pragma unroll
        for (int half = 0; half < 2; half++) {
          unsigned a0 = w8[2 * half][0], c0 = w8[2 * half + 1][0];
          unsigned a1 = w8[2 * half][1], c1 = w8[2 * half + 1][1];
          pl32swap(a0, c0);
          pl32swap(a1, c1);
          pl16swap(a0, c0);
          pl16swap(a1, c1);
          u32x4 w = { a0, a1, c0, c1 };
          *(u32x4*)(dst + half * 512 + lane * 8) = w;
        }
      }
    }
  } else {
    // V: scatter into V^T frag16x64 (verified path)
#pragma unroll
    for (int m = 0; m < 8; m++)
#pragma unroll
      for (int n = 0; n < 4; n++)
#pragma unroll
        for (int r = 0; r < 4; r++) {
          int f = m0 + wr * 128 + m * 16 + lg * 4 + r;
          int t = n0 + wc * 64 + n * 16 + lr;
          float v = acc[m][n][r] + bias[f];
          int c = f - 2 * Dc, head = c >> 6, d = c & 63;
          int bb = t >> 11, tl = t & 2047;
          Vf[(size_t)(bb * 16 + head) * 131072 + (tl >> 6) * 4096
             + fragaddr(d, tl & 63)] = f2bf(v);
        }
  }
}

// ---------------------------------------------------------------------------
// gemm_bt (verified 128x128 structure) -- output projection, fp32 out.
// ---------------------------------------------------------------------------
__global__ __launch_bounds__(256) void gemm_bt(const unsigned short* __restrict__ A,
                                               const unsigned short* __restrict__ Bt,
                                               const float* __restrict__ bias,
                                               float* __restrict__ Cout,
                                               int N, int K) {
  __shared__ unsigned short As[128 * 64];
  __shared__ unsigned short Bs[128 * 64];
  const int tid = threadIdx.x;
  const int lane = tid & 63, wid = tid >> 6;
  const int lr = lane & 15, lg = lane >> 4;
  const int wrow = wid >> 1, wcol = wid & 1;
  const int m0 = blockIdx.y * 128, n0 = blockIdx.x * 128;

  f32x4 acc[4][4] = {};

  for (int k0 = 0; k0 < K; k0 += 64) {
#pragma unroll
    for (int i = 0; i < 4; i++) {
      int ci = i * 256 + tid;
      int row = ci >> 3, ph = ci & 7;
      int cl = ph ^ (row & 7);
      gload_lds16(A + (size_t)(m0 + row) * K + k0 + cl * 8, As + (size_t)(i * 256 + wid * 64) * 8);
      gload_lds16(Bt + (size_t)(n0 + row) * K + k0 + cl * 8, Bs + (size_t)(i * 256 + wid * 64) * 8);
    }
    asm volatile("s_waitcnt vmcnt(0)" ::: "memory");
    __syncthreads();
#pragma unroll
    for (int kk = 0; kk < 2; kk++) {
      bf16x8 av[4], bv[4];
#pragma unroll
      for (int m = 0; m < 4; m++) {
        int row = wrow * 64 + m * 16 + lr;
        int ph = (kk * 4 + lg) ^ (row & 7);
        av[m] = *(const bf16x8*)(As + row * 64 + ph * 8);
      }
#pragma unroll
      for (int n = 0; n < 4; n++) {
        int row = wcol * 64 + n * 16 + lr;
        int ph = (kk * 4 + lg) ^ (row & 7);
        bv[n] = *(const bf16x8*)(Bs + row * 64 + ph * 8);
      }
#pragma unroll
      for (int m = 0; m < 4; m++)
#pragma unroll
        for (int n = 0; n < 4; n++)
          acc[m][n] = mfma16(av[m], bv[n], acc[m][n]);
    }
    __syncthreads();
  }

#pragma unroll
  for (int m = 0; m < 4; m++)
#pragma unroll
    for (int n = 0; n < 4; n++)
#pragma unroll
      for (int r = 0; r < 4; r++) {
        int row = m0 + wrow * 64 + m * 16 + lg * 4 + r;
        int col = n0 + wcol * 64 + n * 16 + lr;
        Cout[(size_t)row * N + col] = acc[m][n][r] + bias[col];
      }
}

// ---------------------------------------------------------------------------
// flash12: flash8 body (verified round-14), tile loop unroll 2 -> 4 so the
// scheduler keeps 2-3 tiles' K/V loads in flight (per-wave prefetch depth is
// the one un-ruled-out limiter; occupancy is 1 block/CU = 2 waves/SIMD
// regardless of VGPR, so register growth is free up to 256).
// 8-wave (512-thread) blocks; grid (4 qb, 64 bh) = 256 blocks; XCD swizzle.
// ---------------------------------------------------------------------------
__global__ __launch_bounds__(512) void flash12(const unsigned short* __restrict__ Qf,
                                               const unsigned short* __restrict__ Kf,
                                               const unsigned short* __restrict__ Vf,
                                               const int* __restrict__ mask,
                                               unsigned short* __restrict__ merged) {
  const int tid = threadIdx.x;
  const int lane = tid & 63, wid = tid >> 6;   // wid 0..7
  const int lr = lane & 15, lg = lane >> 4;

  const int lin = blockIdx.y * 4 + blockIdx.x;      // 0..255
  const int swz = (lin & 7) * 32 + (lin >> 3);
  const int qb = swz & 3, bh = swz >> 2;
  const int b = bh >> 4, h = bh & 15;
  const int wq = qb * 512 + wid * 64;               // wave's q base

  const unsigned short* Qb = Qf + (size_t)bh * 131072;
  const unsigned short* Kb = Kf + (size_t)bh * 131072;
  const unsigned short* Vb = Vf + (size_t)bh * 131072;

  bf16x8 qf[4][2];
#pragma unroll
  for (int qn = 0; qn < 4; qn++)
#pragma unroll
    for (int kk = 0; kk < 2; kk++)
      qf[qn][kk] = *(const bf16x8*)(Qb + ((wq >> 4) + qn) * 1024 + kk * 512 + lane * 8);

  f32x4 o[4][4] = {};
  f32x4 lacc[4] = {};

  bf16x8 ones;
#pragma unroll
  for (int j = 0; j < 8; j++) ones[j] = (bf16_t)1.0f;

  // whole-mask all-ones check (8 coalesced int4 loads), hoisted
  bool allone = true;
#pragma unroll
  for (int j = 0; j < 8; j++) {
    int4 mv = ((const int4*)mask)[j * 64 + lane];
    allone = allone && (mv.x != 0) && (mv.y != 0) && (mv.z != 0) && (mv.w != 0);
  }
  const bool nomask = (__ballot(allone) == ~0ull);

#pragma unroll 4
  for (int tile = 0; tile < 32; tile++) {
    bf16x8 kf[4][2];
#pragma unroll
    for (int n = 0; n < 4; n++)
#pragma unroll
      for (int kk = 0; kk < 2; kk++)
        kf[n][kk] = *(const bf16x8*)(Kb + (tile * 4 + n) * 1024 + kk * 512 + lane * 8);
    bf16x8 vf[4][2];
#pragma unroll
    for (int dn = 0; dn < 4; dn++)
#pragma unroll
      for (int kk = 0; kk < 2; kk++)
        vf[dn][kk] = *(const bf16x8*)(Vb + tile * 4096 + dn * 1024 + kk * 512 + lane * 8);

    unsigned long long mb = ~0ull;
    if (!nomask) mb = __ballot(mask[tile * 64 + lane] != 0);

    unsigned pk[4][4][2];
#pragma unroll
    for (int kvn = 0; kvn < 4; kvn++) {
      f32x4 st[4] = {};
#pragma unroll
      for (int qn = 0; qn < 4; qn++) {
        st[qn] = mfma16(kf[kvn][0], qf[qn][0], st[qn]);
        st[qn] = mfma16(kf[kvn][1], qf[qn][1], st[qn]);
      }
      if (mb != ~0ull) {
#pragma unroll
        for (int r = 0; r < 4; r++)
          if (!((mb >> (kvn * 16 + lg * 4 + r)) & 1ull)) {
#pragma unroll
            for (int qn = 0; qn < 4; qn++) st[qn][r] = -1e30f;
          }
      }
#pragma unroll
      for (int qn = 0; qn < 4; qn++) {
        float e[4];
#pragma unroll
        for (int r = 0; r < 4; r++)
          asm("v_exp_f32 %0, %1" : "=v"(e[r]) : "v"(st[qn][r]));
        asm("v_cvt_pk_bf16_f32 %0, %1, %2" : "=v"(pk[qn][kvn][0]) : "v"(e[0]), "v"(e[1]));
        asm("v_cvt_pk_bf16_f32 %0, %1, %2" : "=v"(pk[qn][kvn][1]) : "v"(e[2]), "v"(e[3]));
      }
    }

    bf16x8 pa[4][2];
#pragma unroll
    for (int qn = 0; qn < 4; qn++)
#pragma unroll
      for (int m = 0; m < 2; m++) {
        unsigned a0 = pk[qn][2 * m][0], b0 = pk[qn][2 * m + 1][0];
        unsigned a1 = pk[qn][2 * m][1], b1 = pk[qn][2 * m + 1][1];
        pl32swap(a0, b0);
        pl32swap(a1, b1);
        pl16swap(a0, b0);
        pl16swap(a1, b1);
        u32x4 w = { a0, a1, b0, b1 };
        pa[qn][m] = __builtin_bit_cast(bf16x8, w);
      }

    __builtin_amdgcn_s_setprio(1);
#pragma unroll
    for (int qn = 0; qn < 4; qn++) {
#pragma unroll
      for (int dn = 0; dn < 4; dn++) {
        o[qn][dn] = mfma16(pa[qn][0], vf[dn][0], o[qn][dn]);
        o[qn][dn] = mfma16(pa[qn][1], vf[dn][1], o[qn][dn]);
      }
      lacc[qn] = mfma16(pa[qn][0], ones, lacc[qn]);
      lacc[qn] = mfma16(pa[qn][1], ones, lacc[qn]);
    }
    __builtin_amdgcn_s_setprio(0);
  }

  // epilogue: normalize and store
#pragma unroll
  for (int qn = 0; qn < 4; qn++)
#pragma unroll
    for (int r = 0; r < 4; r++) {
      float inv = 1.0f / lacc[qn][r];
      int grow = b * Tc + wq + qn * 16 + lg * 4 + r;
#pragma unroll
      for (int dn = 0; dn < 4; dn++) {
        int gcol = h * HDc + dn * 16 + lr;
        merged[(size_t)grow * Dc + gcol] = f2bf(o[qn][dn][r] * inv);
      }
    }
}

// ---------------------------------------------------------------------------
extern "C" void kernel_launch(void* const* d_in, const int* in_sizes, int n_in,
                              void* d_out, int out_size, void* d_ws, size_t ws_size,
                              hipStream_t stream) {
  const float* embed = (const float*)d_in[0];
  const int*   mask  = (const int*)d_in[1];
  const float* Wq = (const float*)d_in[2];
  const float* bq = (const float*)d_in[3];
  const float* Wk = (const float*)d_in[4];
  const float* bk = (const float*)d_in[5];
  const float* Wv = (const float*)d_in[6];
  const float* bv = (const float*)d_in[7];
  const float* Wo = (const float*)d_in[8];
  const float* bo = (const float*)d_in[9];
  float* out = (float*)d_out;

  char* ws = (char*)d_ws;
  unsigned short* embed_bf = (unsigned short*)ws; ws += (size_t)Mc * Dc * 2;        // 16.8 MB
  unsigned short* WtAll    = (unsigned short*)ws; ws += (size_t)4 * Dc * Dc * 2;    //  8.4 MB
  float*          ball     = (float*)ws;          ws += 16384;
  unsigned short* Qf       = (unsigned short*)ws; ws += (size_t)Mc * Dc * 2;        // 16.8 MB
  unsigned short* Kf       = (unsigned short*)ws; ws += (size_t)Mc * Dc * 2;        // 16.8 MB
  unsigned short* Vf       = (unsigned short*)ws; ws += (size_t)Mc * Dc * 2;        // 16.8 MB
  unsigned short* merged   = (unsigned short*)ws; ws += (size_t)Mc * Dc * 2;        // 16.8 MB

  prep<<<8192 + 1024 + 1, 256, 0, stream>>>(embed, Wq, Wk, Wv, Wo, bq, bk, bv,
                                            embed_bf, WtAll, ball);
  gemm_qkv11<<<dim3(12, 32), 512, 0, stream>>>(WtAll, embed_bf, ball, Qf, Kf, Vf);
  flash12<<<dim3(4, 64), 512, 0, stream>>>(Qf, Kf, Vf, mask, merged);
  gemm_bt<<<dim3(8, 64), 256, 0, stream>>>(merged, WtAll + (size_t)3 * Dc * Dc, bo, out, Dc, Dc);
}